// Round 1
// baseline (5790.316 us; speedup 1.0000x reference)
//
#include <hip/hip_runtime.h>
#include <hip/hip_bf16.h>

// ---------------------------------------------------------------------------
// LSTM LM forward on MI355X.
// Pipeline: prep (weight split/concat, dec_w->bf16, embed gather) ->
// 129 pipelined step launches (layer0(t) || layer1(t-1)) -> bf16 MFMA decode.
// Recurrent weights split hi+lo bf16 for precision; c-state fp32.
// ---------------------------------------------------------------------------

#define NVOC 32000
#define DIM  512
#define HID  512
#define SEQ  128
#define BAT  32

typedef short s8v __attribute__((ext_vector_type(8)));
typedef short s4v __attribute__((ext_vector_type(4)));
typedef float f4v __attribute__((ext_vector_type(4)));

__device__ __forceinline__ short f2bf(float f) {
    unsigned u = __builtin_bit_cast(unsigned, f);
    unsigned r = (u + 0x7fffu + ((u >> 16) & 1u)) >> 16;
    return (short)r;
}
__device__ __forceinline__ float bf2f(short s) {
    unsigned u = ((unsigned)(unsigned short)s) << 16;
    return __builtin_bit_cast(float, u);
}
__device__ __forceinline__ float sigm(float x) { return 1.f / (1.f + __expf(-x)); }

__device__ __forceinline__ f4v mf16(s8v a, s8v b, f4v c) {
    return __builtin_amdgcn_mfma_f32_16x16x32_bf16(a, b, c, 0, 0, 0);
}

// --- prep: Wcat[l][row][0:512]=W_l[row], [512:1024]=U_l[row]; split hi/lo ---
__global__ __launch_bounds__(256) void prep_w(
    const float* __restrict__ W0, const float* __restrict__ W1,
    const float* __restrict__ U0, const float* __restrict__ U1,
    short* __restrict__ whi, short* __restrict__ wlo)
{
    int id = blockIdx.x * 256 + threadIdx.x;          // 2*2048*1024
    if (id >= 2 * 2048 * 1024) return;
    int layer = id >> 21;
    int rem   = id & (2048 * 1024 - 1);
    int row   = rem >> 10;
    int k     = rem & 1023;
    const float* Wm = layer ? W1 : W0;
    const float* Um = layer ? U1 : U0;
    float v = (k < 512) ? Wm[row * 512 + k] : Um[row * 512 + (k - 512)];
    short hi = f2bf(v);
    short lo = f2bf(v - bf2f(hi));
    whi[id] = hi;
    wlo[id] = lo;
}

__global__ __launch_bounds__(256) void prep_dec(const float* __restrict__ dw,
                                                short* __restrict__ dbf)
{
    int id = blockIdx.x * 256 + threadIdx.x;          // x4 elems
    if (id >= (NVOC * DIM) / 4) return;
    int e = id * 4;
    float4 v = *(const float4*)(dw + e);
    s4v o; o[0] = f2bf(v.x); o[1] = f2bf(v.y); o[2] = f2bf(v.z); o[3] = f2bf(v.w);
    *(s4v*)(dbf + e) = o;
}

// xcat[t][b] = [ x_t(b) bf16 (512) | h0(t-1,b) bf16 (512) ]
__global__ __launch_bounds__(256) void embed_k(const int* __restrict__ toks,
                                               const float* __restrict__ emb,
                                               short* __restrict__ xcat)
{
    int id = blockIdx.x * 256 + threadIdx.x;          // x4 elems over 4096*512
    if (id >= (SEQ * BAT * DIM) / 4) return;
    int e  = id * 4;
    int tb = e >> 9;
    int k4 = e & 511;
    int tok = toks[tb];
    float4 v = *(const float4*)(emb + (size_t)tok * DIM + k4);
    s4v o; o[0] = f2bf(v.x); o[1] = f2bf(v.y); o[2] = f2bf(v.z); o[3] = f2bf(v.w);
    *(s4v*)(xcat + (size_t)tb * 1024 + k4) = o;
}

__global__ __launch_bounds__(256) void init_k(float* __restrict__ cst,
                                              short* __restrict__ xcat,
                                              short* __restrict__ hcat)
{
    int id = blockIdx.x * 256 + threadIdx.x;
    if (id < 2 * BAT * HID) cst[id] = 0.f;
    if (id < BAT * HID) {
        int b = id >> 9, k = id & 511;
        xcat[b * 1024 + 512 + k] = 0;
        hcat[b * 1024 + 512 + k] = 0;
    }
}

// --- one pipelined step: blocks 0..7 layer0(step t), blocks 8..15 layer1(t-1)
// Per block: gate tile [32 b x 64 j x 4 gates], K=1024, hi+lo weight MFMAs.
// hcat[t][b] = [ h0(t,b) | h1(t-1,b) ]
__global__ __launch_bounds__(256) void step_k(
    const short* __restrict__ whi, const short* __restrict__ wlo,
    const float* __restrict__ bias,
    short* __restrict__ xcat, short* __restrict__ hcat,
    short* __restrict__ adec, float* __restrict__ cst, int t)
{
    const int layer = blockIdx.x >> 3;
    const int jb    = (blockIdx.x & 7) * 64;
    if (layer == 0 && t >= SEQ) return;
    if (layer == 1 && t < 1) return;
    const int s = (layer == 0) ? t : (t - 1);

    const short* Ag = (layer == 0) ? (xcat + (size_t)s * BAT * 1024)
                                   : (hcat + (size_t)s * BAT * 1024);
    const short* WH = whi + (size_t)layer * 2048 * 1024;
    const short* WL = wlo + (size_t)layer * 2048 * 1024;
    float* C = cst + layer * BAT * HID;

    __shared__ short Alds[32][1032];   // pad 8 shorts -> 2064B row stride (2-way banks)
    {
        const int tid = threadIdx.x;
        #pragma unroll
        for (int i = 0; i < 16; ++i) {
            int c    = tid + i * 256;          // 0..4095 chunks of 8 shorts
            int row  = c >> 7;
            int col8 = (c & 127) << 3;
            *(s8v*)&Alds[row][col8] = *(const s8v*)(Ag + row * 1024 + col8);
        }
    }
    __syncthreads();

    const int l  = threadIdx.x & 63;
    const int w  = threadIdx.x >> 6;
    const int jw = jb + w * 16;
    const int lr = l & 15;
    const int kg = l >> 4;

    f4v acc[4][2];
    #pragma unroll
    for (int g = 0; g < 4; ++g)
        #pragma unroll
        for (int mt = 0; mt < 2; ++mt) {
            acc[g][mt][0] = 0.f; acc[g][mt][1] = 0.f;
            acc[g][mt][2] = 0.f; acc[g][mt][3] = 0.f;
        }

    for (int ks = 0; ks < 32; ++ks) {
        int k = ks * 32 + kg * 8;
        s8v a0 = *(const s8v*)&Alds[lr][k];
        s8v a1 = *(const s8v*)&Alds[16 + lr][k];
        #pragma unroll
        for (int g = 0; g < 4; ++g) {
            int row = g * 512 + jw + lr;
            s8v bh = *(const s8v*)(WH + (size_t)row * 1024 + k);
            s8v bl = *(const s8v*)(WL + (size_t)row * 1024 + k);
            acc[g][0] = mf16(a0, bh, acc[g][0]);
            acc[g][1] = mf16(a1, bh, acc[g][1]);
            acc[g][0] = mf16(a0, bl, acc[g][0]);
            acc[g][1] = mf16(a1, bl, acc[g][1]);
        }
    }

    // pointwise LSTM update, fully in-register (i/f/g/o aligned per lane/reg)
    const int j = jw + lr;
    const float bi = bias[j], bff = bias[512 + j], bg = bias[1024 + j], bo = bias[1536 + j];
    #pragma unroll
    for (int mt = 0; mt < 2; ++mt) {
        #pragma unroll
        for (int r = 0; r < 4; ++r) {
            int b = mt * 16 + kg * 4 + r;
            float gi = sigm(acc[0][mt][r] + bi);
            float gf = sigm(acc[1][mt][r] + bff);
            float gg = tanhf(acc[2][mt][r] + bg);
            float go = sigm(acc[3][mt][r] + bo);
            float co = C[b * HID + j];
            float cn = gf * co + gi * gg;
            C[b * HID + j] = cn;
            short hb = f2bf(go * tanhf(cn));
            if (layer == 0) {
                hcat[((size_t)s * BAT + b) * 1024 + j] = hb;           // layer1 input, step s
                xcat[((size_t)(s + 1) * BAT + b) * 1024 + 512 + j] = hb; // recurrent, step s+1
            } else {
                adec[((size_t)s * BAT + b) * HID + j] = hb;            // decoder A row
                hcat[((size_t)(s + 1) * BAT + b) * 1024 + 512 + j] = hb;
            }
        }
    }
}

// --- decoder: C[4096][32000] = adec @ dec_w^T + dec_b (bf16 MFMA, fp32 out) --
__global__ __launch_bounds__(256) void dec_gemm(
    const short* __restrict__ A,    // [4096][512] bf16
    const short* __restrict__ Bw,   // [32000][512] bf16
    const float* __restrict__ bias, // [32000]
    float* __restrict__ out)        // [4096][32000]
{
    const int nb = blockIdx.x % 250, mb = blockIdx.x / 250;
    const int m0 = mb * 128, n0 = nb * 128;
    __shared__ short Alds[128][40];  // +8 pad: 80B row stride, ~2-way banks
    __shared__ short Blds[128][40];
    const int tid = threadIdx.x, l = tid & 63, w = tid >> 6;
    const int wr = w >> 1, wc = w & 1;
    const int lr = l & 15, kg = l >> 4;

    f4v acc[4][4];
    #pragma unroll
    for (int mi = 0; mi < 4; ++mi)
        #pragma unroll
        for (int ni = 0; ni < 4; ++ni) {
            acc[mi][ni][0] = 0.f; acc[mi][ni][1] = 0.f;
            acc[mi][ni][2] = 0.f; acc[mi][ni][3] = 0.f;
        }

    for (int kt = 0; kt < 16; ++kt) {
        #pragma unroll
        for (int i = 0; i < 2; ++i) {
            int c = tid + i * 256;             // 512 chunks of 8 shorts each matrix
            int row = c >> 2, q = (c & 3) << 3;
            *(s8v*)&Alds[row][q] = *(const s8v*)(A  + (size_t)(m0 + row) * 512 + kt * 32 + q);
            *(s8v*)&Blds[row][q] = *(const s8v*)(Bw + (size_t)(n0 + row) * 512 + kt * 32 + q);
        }
        __syncthreads();
        s8v af[4], bfr[4];
        #pragma unroll
        for (int i = 0; i < 4; ++i) {
            af[i]  = *(const s8v*)&Alds[wr * 64 + i * 16 + lr][kg * 8];
            bfr[i] = *(const s8v*)&Blds[wc * 64 + i * 16 + lr][kg * 8];
        }
        #pragma unroll
        for (int mi = 0; mi < 4; ++mi)
            #pragma unroll
            for (int ni = 0; ni < 4; ++ni)
                acc[mi][ni] = mf16(af[mi], bfr[ni], acc[mi][ni]);
        __syncthreads();
    }

    #pragma unroll
    for (int mi = 0; mi < 4; ++mi)
        #pragma unroll
        for (int ni = 0; ni < 4; ++ni) {
            int n = n0 + wc * 64 + ni * 16 + lr;
            float bb = bias[n];
            #pragma unroll
            for (int r = 0; r < 4; ++r) {
                int m = m0 + wr * 64 + mi * 16 + kg * 4 + r;
                out[(size_t)m * NVOC + n] = acc[mi][ni][r] + bb;
            }
        }
}

extern "C" void kernel_launch(void* const* d_in, const int* in_sizes, int n_in,
                              void* d_out, int out_size, void* d_ws, size_t ws_size,
                              hipStream_t stream)
{
    const int*   toks = (const int*)d_in[0];
    const float* emb  = (const float*)d_in[1];
    const float* W0   = (const float*)d_in[2];
    const float* W1   = (const float*)d_in[3];
    const float* U0   = (const float*)d_in[4];
    const float* U1   = (const float*)d_in[5];
    const float* bias = (const float*)d_in[6];
    const float* dw   = (const float*)d_in[7];
    const float* db   = (const float*)d_in[8];
    float* out = (float*)d_out;

    char* ws = (char*)d_ws;
    size_t off = 0;
    auto alloc = [&](size_t bytes) -> void* {
        void* p = ws + off;
        off += (bytes + 255) & ~(size_t)255;
        return p;
    };
    short* whi  = (short*)alloc(2ull * 2048 * 1024 * 2);
    short* wlo  = (short*)alloc(2ull * 2048 * 1024 * 2);
    short* dbf  = (short*)alloc((size_t)NVOC * DIM * 2);
    short* xcat = (short*)alloc(129ull * BAT * 1024 * 2);
    short* hcat = (short*)alloc(129ull * BAT * 1024 * 2);
    short* adec = (short*)alloc((size_t)SEQ * BAT * HID * 2);
    float* cst  = (float*)alloc(2ull * BAT * HID * 4);

    prep_w  <<<16384, 256, 0, stream>>>(W0, W1, U0, U1, whi, wlo);
    prep_dec<<<(NVOC * DIM / 4 + 255) / 256, 256, 0, stream>>>(dw, dbf);
    embed_k <<<(SEQ * BAT * DIM / 4 + 255) / 256, 256, 0, stream>>>(toks, emb, xcat);
    init_k  <<<128, 256, 0, stream>>>(cst, xcat, hcat);

    for (int t = 0; t <= SEQ; ++t)
        step_k<<<16, 256, 0, stream>>>(whi, wlo, bias, xcat, hcat, adec, cst, t);

    dec_gemm<<<(SEQ * BAT / 128) * (NVOC / 128), 256, 0, stream>>>(adec, dbf, db, out);
}

// Round 2
// 2753.916 us; speedup vs baseline: 2.1026x; 2.1026x over previous
//
#include <hip/hip_runtime.h>
#include <hip/hip_bf16.h>

// ---------------------------------------------------------------------------
// LSTM LM forward on MI355X — round 2.
// Persistent recurrence kernel: 64 blocks (32 per layer), weights resident in
// VGPRs as hi+lo bf16 MFMA fragments (256 VGPR/wave), cell state in registers,
// custom device-scope grid barrier between the 129 pipelined steps.
// Decoder: 128x128-tile bf16 MFMA GEMM (near HBM-write roofline).
// ---------------------------------------------------------------------------

#define NVOC 32000
#define DIM  512
#define HID  512
#define SEQ  128
#define BAT  32
#define NB   64      // blocks in persistent kernel

typedef short s8v __attribute__((ext_vector_type(8)));
typedef short s4v __attribute__((ext_vector_type(4)));
typedef float f4v __attribute__((ext_vector_type(4)));

__device__ __forceinline__ short f2bf(float f) {
    unsigned u = __builtin_bit_cast(unsigned, f);
    unsigned r = (u + 0x7fffu + ((u >> 16) & 1u)) >> 16;
    return (short)r;
}
__device__ __forceinline__ float bf2f(short s) {
    unsigned u = ((unsigned)(unsigned short)s) << 16;
    return __builtin_bit_cast(float, u);
}
__device__ __forceinline__ float sigm(float x) { return 1.f / (1.f + __expf(-x)); }

__device__ __forceinline__ f4v mf16(s8v a, s8v b, f4v c) {
    return __builtin_amdgcn_mfma_f32_16x16x32_bf16(a, b, c, 0, 0, 0);
}

// ---------------- prep kernels ---------------------------------------------
__global__ __launch_bounds__(256) void prep_dec(const float* __restrict__ dw,
                                                short* __restrict__ dbf)
{
    int id = blockIdx.x * 256 + threadIdx.x;          // x4 elems
    if (id >= (NVOC * DIM) / 4) return;
    int e = id * 4;
    float4 v = *(const float4*)(dw + e);
    s4v o; o[0] = f2bf(v.x); o[1] = f2bf(v.y); o[2] = f2bf(v.z); o[3] = f2bf(v.w);
    *(s4v*)(dbf + e) = o;
}

// xemb[t*32+b][512] bf16
__global__ __launch_bounds__(256) void embed_k(const int* __restrict__ toks,
                                               const float* __restrict__ emb,
                                               short* __restrict__ xemb)
{
    int id = blockIdx.x * 256 + threadIdx.x;          // x4 elems over 4096*512
    if (id >= (SEQ * BAT * DIM) / 4) return;
    int e  = id * 4;
    int tb = e >> 9;
    int k4 = e & 511;
    int tok = toks[tb];
    float4 v = *(const float4*)(emb + (size_t)tok * DIM + k4);
    s4v o; o[0] = f2bf(v.x); o[1] = f2bf(v.y); o[2] = f2bf(v.z); o[3] = f2bf(v.w);
    *(s4v*)(xemb + e) = o;
}

// zero h buffers [2 layer][2 parity][32][512] + barrier counter
__global__ __launch_bounds__(256) void init_k(short* __restrict__ hbuf,
                                              unsigned* __restrict__ bar)
{
    int id = blockIdx.x * 256 + threadIdx.x;
    if (id < 2 * 2 * BAT * HID) hbuf[id] = 0;
    if (id == 0) *bar = 0;
}

// ---------------- persistent recurrence ------------------------------------
// 64 blocks x 256 threads. Block bl: layer = bl>>5, j-slice j0=(bl&31)*16.
// Wave w (=gate) holds rows {w*512 + j0 + 0..15} x K=1024 as hi/lo fragments.
__global__ __launch_bounds__(256, 1) void rnn_k(
    const float* __restrict__ W0, const float* __restrict__ W1,
    const float* __restrict__ U0, const float* __restrict__ U1,
    const float* __restrict__ bias,
    const short* __restrict__ xemb,
    short* __restrict__ hbuf,    // [2][2][32][512] bf16
    short* __restrict__ adec,    // [128*32][512] bf16
    unsigned* __restrict__ bar)
{
    const int tid   = threadIdx.x;
    const int bl    = blockIdx.x;
    const int layer = bl >> 5;
    const int j0    = (bl & 31) * 16;
    const int w     = tid >> 6;       // wave index == gate index
    const int l     = tid & 63;
    const int lr    = l & 15;
    const int kg    = l >> 4;

    __shared__ short Alds[32][1032];          // 2064B row stride: ~2-way banks
    __shared__ float gbuf[4][16][33];         // [gate][j][batch(+pad)]

    // --- one-time: load weight slice fp32 -> hi/lo bf16 fragments in VGPRs ---
    const float* Wl = layer ? W1 : W0;
    const float* Ul = layer ? U1 : U0;
    const int gr = w * 512 + j0 + lr;         // gate-row in [0,2048)
    s8v wh[32], wlo[32];
    #pragma unroll
    for (int ks = 0; ks < 32; ++ks) {
        const float* src = (ks < 16)
            ? (Wl + (size_t)gr * 512 + ks * 32 + kg * 8)
            : (Ul + (size_t)gr * 512 + (ks - 16) * 32 + kg * 8);
        float4 va = *(const float4*)src;
        float4 vb = *(const float4*)(src + 4);
        float vv[8] = {va.x, va.y, va.z, va.w, vb.x, vb.y, vb.z, vb.w};
        s8v hi, lo;
        #pragma unroll
        for (int e = 0; e < 8; ++e) {
            short h = f2bf(vv[e]);
            hi[e] = h;
            lo[e] = f2bf(vv[e] - bf2f(h));
        }
        wh[ks] = hi; wlo[ks] = lo;
    }

    // --- epilogue ownership: thread -> (batch eb, j pair ej,ej+1); c in regs -
    const int eb  = tid >> 3;                 // 0..31
    const int ej  = (tid & 7) * 2;            // 0,2,..,14
    const int jg0 = j0 + ej, jg1 = jg0 + 1;
    const float bi0 = bias[jg0],        bi1 = bias[jg1];
    const float bf0 = bias[512 + jg0],  bf1 = bias[512 + jg1];
    const float bg0 = bias[1024 + jg0], bg1 = bias[1024 + jg1];
    const float bo0 = bias[1536 + jg0], bo1 = bias[1536 + jg1];
    float c0 = 0.f, c1 = 0.f;

    short* Hme = hbuf + (size_t)layer * 2 * BAT * HID;  // my layer's dbl-buffer
    const short* H0b = hbuf;                            // layer0 h (both read)

    for (int it = 0; it <= SEQ; ++it) {
        const bool active = (layer == 0) ? (it < SEQ) : (it >= 1);
        const int rp = it & 1, wp = rp ^ 1;

        if (active) {
            const short* sA = (layer == 0) ? (xemb + (size_t)it * BAT * HID)
                                           : (H0b + rp * BAT * HID);
            const short* sB = (layer == 0) ? (H0b + rp * BAT * HID)
                                           : (Hme + rp * BAT * HID);
            #pragma unroll
            for (int i = 0; i < 16; ++i) {
                int c    = tid + i * 256;     // 4096 chunks of 8 shorts
                int half = c >> 11;
                int cc   = c & 2047;
                int row  = cc >> 6;
                int col8 = (cc & 63) * 8;
                const short* s = half ? sB : sA;
                *(s8v*)&Alds[row][half * 512 + col8] =
                    *(const s8v*)(s + row * HID + col8);
            }
        }
        __syncthreads();

        if (active) {
            f4v acc0, acc1;
            acc0[0]=0.f; acc0[1]=0.f; acc0[2]=0.f; acc0[3]=0.f;
            acc1 = acc0;
            #pragma unroll
            for (int ks = 0; ks < 32; ++ks) {
                const int k = ks * 32 + kg * 8;
                s8v a0 = *(const s8v*)&Alds[lr][k];
                s8v a1 = *(const s8v*)&Alds[16 + lr][k];
                acc0 = mf16(a0, wh[ks],  acc0);
                acc0 = mf16(a0, wlo[ks], acc0);
                acc1 = mf16(a1, wh[ks],  acc1);
                acc1 = mf16(a1, wlo[ks], acc1);
            }
            #pragma unroll
            for (int r = 0; r < 4; ++r) {
                gbuf[w][lr][kg * 4 + r]      = acc0[r];
                gbuf[w][lr][16 + kg * 4 + r] = acc1[r];
            }
        }
        __syncthreads();

        if (active) {
            float gi0 = sigm(gbuf[0][ej][eb]     + bi0);
            float gi1 = sigm(gbuf[0][ej + 1][eb] + bi1);
            float gf0 = sigm(gbuf[1][ej][eb]     + bf0);
            float gf1 = sigm(gbuf[1][ej + 1][eb] + bf1);
            float gg0 = tanhf(gbuf[2][ej][eb]     + bg0);
            float gg1 = tanhf(gbuf[2][ej + 1][eb] + bg1);
            float go0 = sigm(gbuf[3][ej][eb]     + bo0);
            float go1 = sigm(gbuf[3][ej + 1][eb] + bo1);
            c0 = gf0 * c0 + gi0 * gg0;
            c1 = gf1 * c1 + gi1 * gg1;
            short h0s = f2bf(go0 * tanhf(c0));
            short h1s = f2bf(go1 * tanhf(c1));
            int hw = (int)(unsigned short)h0s | ((int)(unsigned short)h1s << 16);
            *(int*)(Hme + wp * BAT * HID + eb * HID + jg0) = hw;
            if (layer == 1)
                *(int*)(adec + ((size_t)(it - 1) * BAT + eb) * HID + jg0) = hw;
        }

        if (it < SEQ) {
            __threadfence();                  // release my stores (all threads)
            __syncthreads();
            if (tid == 0) {
                __hip_atomic_fetch_add(bar, 1u, __ATOMIC_RELEASE,
                                       __HIP_MEMORY_SCOPE_AGENT);
                const unsigned target = (unsigned)NB * (unsigned)(it + 1);
                while (__hip_atomic_load(bar, __ATOMIC_ACQUIRE,
                                         __HIP_MEMORY_SCOPE_AGENT) < target)
                    __builtin_amdgcn_s_sleep(1);
            }
            __syncthreads();
            __threadfence();                  // acquire: invalidate stale cache
        }
    }
}

// ---------------- decoder GEMM ---------------------------------------------
__global__ __launch_bounds__(256) void dec_gemm(
    const short* __restrict__ A,    // [4096][512] bf16
    const short* __restrict__ Bw,   // [32000][512] bf16
    const float* __restrict__ bias, // [32000]
    float* __restrict__ out)        // [4096][32000]
{
    const int nb = blockIdx.x % 250, mb = blockIdx.x / 250;
    const int m0 = mb * 128, n0 = nb * 128;
    __shared__ short Alds[128][40];
    __shared__ short Blds[128][40];
    const int tid = threadIdx.x, l = tid & 63, w = tid >> 6;
    const int wr = w >> 1, wc = w & 1;
    const int lr = l & 15, kg = l >> 4;

    f4v acc[4][4];
    #pragma unroll
    for (int mi = 0; mi < 4; ++mi)
        #pragma unroll
        for (int ni = 0; ni < 4; ++ni) {
            acc[mi][ni][0] = 0.f; acc[mi][ni][1] = 0.f;
            acc[mi][ni][2] = 0.f; acc[mi][ni][3] = 0.f;
        }

    for (int kt = 0; kt < 16; ++kt) {
        #pragma unroll
        for (int i = 0; i < 2; ++i) {
            int c = tid + i * 256;
            int row = c >> 2, q = (c & 3) << 3;
            *(s8v*)&Alds[row][q] = *(const s8v*)(A  + (size_t)(m0 + row) * 512 + kt * 32 + q);
            *(s8v*)&Blds[row][q] = *(const s8v*)(Bw + (size_t)(n0 + row) * 512 + kt * 32 + q);
        }
        __syncthreads();
        s8v af[4], bfr[4];
        #pragma unroll
        for (int i = 0; i < 4; ++i) {
            af[i]  = *(const s8v*)&Alds[wr * 64 + i * 16 + lr][kg * 8];
            bfr[i] = *(const s8v*)&Blds[wc * 64 + i * 16 + lr][kg * 8];
        }
        #pragma unroll
        for (int mi = 0; mi < 4; ++mi)
            #pragma unroll
            for (int ni = 0; ni < 4; ++ni)
                acc[mi][ni] = mf16(af[mi], bfr[ni], acc[mi][ni]);
        __syncthreads();
    }

    #pragma unroll
    for (int mi = 0; mi < 4; ++mi)
        #pragma unroll
        for (int ni = 0; ni < 4; ++ni) {
            int n = n0 + wc * 64 + ni * 16 + lr;
            float bb = bias[n];
            #pragma unroll
            for (int r = 0; r < 4; ++r) {
                int m = m0 + wr * 64 + mi * 16 + kg * 4 + r;
                out[(size_t)m * NVOC + n] = acc[mi][ni][r] + bb;
            }
        }
}

extern "C" void kernel_launch(void* const* d_in, const int* in_sizes, int n_in,
                              void* d_out, int out_size, void* d_ws, size_t ws_size,
                              hipStream_t stream)
{
    const int*   toks = (const int*)d_in[0];
    const float* emb  = (const float*)d_in[1];
    const float* W0   = (const float*)d_in[2];
    const float* W1   = (const float*)d_in[3];
    const float* U0   = (const float*)d_in[4];
    const float* U1   = (const float*)d_in[5];
    const float* bias = (const float*)d_in[6];
    const float* dw   = (const float*)d_in[7];
    const float* db   = (const float*)d_in[8];
    float* out = (float*)d_out;

    char* ws = (char*)d_ws;
    size_t off = 0;
    auto alloc = [&](size_t bytes) -> void* {
        void* p = ws + off;
        off += (bytes + 255) & ~(size_t)255;
        return p;
    };
    short*    dbf  = (short*)alloc((size_t)NVOC * DIM * 2);
    short*    xemb = (short*)alloc((size_t)SEQ * BAT * DIM * 2);
    short*    hbuf = (short*)alloc(2ull * 2 * BAT * HID * 2);
    short*    adec = (short*)alloc((size_t)SEQ * BAT * HID * 2);
    unsigned* bar  = (unsigned*)alloc(256);

    prep_dec<<<(NVOC * DIM / 4 + 255) / 256, 256, 0, stream>>>(dw, dbf);
    embed_k <<<(SEQ * BAT * DIM / 4 + 255) / 256, 256, 0, stream>>>(toks, emb, xemb);
    init_k  <<<256, 256, 0, stream>>>(hbuf, bar);

    rnn_k<<<NB, 256, 0, stream>>>(W0, W1, U0, U1, bias, xemb, hbuf, adec, bar);

    dec_gemm<<<(SEQ * BAT / 128) * (NVOC / 128), 256, 0, stream>>>(adec, dbf, db, out);
}

// Round 3
// 1875.114 us; speedup vs baseline: 3.0880x; 1.4687x over previous
//
#include <hip/hip_runtime.h>
#include <hip/hip_bf16.h>

// ---------------------------------------------------------------------------
// LSTM LM forward on MI355X — round 3.
// Persistent recurrence kernel (64 blocks, weights VGPR-resident as hi+lo
// bf16 fragments). Cross-XCD communication via write-through agent-scope
// atomics on the h-buffers only; per-block flag barrier (no threadfence,
// no L2 writeback/invalidate). Decoder: 128x128 bf16 MFMA GEMM.
// ---------------------------------------------------------------------------

#define NVOC 32000
#define DIM  512
#define HID  512
#define SEQ  128
#define BAT  32
#define NB   64      // blocks in persistent kernel

typedef short s8v __attribute__((ext_vector_type(8)));
typedef short s4v __attribute__((ext_vector_type(4)));
typedef float f4v __attribute__((ext_vector_type(4)));
typedef unsigned long long u64;

__device__ __forceinline__ short f2bf(float f) {
    unsigned u = __builtin_bit_cast(unsigned, f);
    unsigned r = (u + 0x7fffu + ((u >> 16) & 1u)) >> 16;
    return (short)r;
}
__device__ __forceinline__ float bf2f(short s) {
    unsigned u = ((unsigned)(unsigned short)s) << 16;
    return __builtin_bit_cast(float, u);
}
__device__ __forceinline__ float sigm(float x) { return 1.f / (1.f + __expf(-x)); }

__device__ __forceinline__ f4v mf16(s8v a, s8v b, f4v c) {
    return __builtin_amdgcn_mfma_f32_16x16x32_bf16(a, b, c, 0, 0, 0);
}

// coherent (cross-XCD) 8B load / 4B store, bypassing L1+L2
__device__ __forceinline__ u64 cohload8(const short* p) {
    return __hip_atomic_load((const u64*)p, __ATOMIC_RELAXED,
                             __HIP_MEMORY_SCOPE_AGENT);
}
__device__ __forceinline__ void cohstore4(short* p, unsigned v) {
    __hip_atomic_store((unsigned*)p, v, __ATOMIC_RELAXED,
                       __HIP_MEMORY_SCOPE_AGENT);
}

// ---------------- prep kernels ---------------------------------------------
__global__ __launch_bounds__(256) void prep_dec(const float* __restrict__ dw,
                                                short* __restrict__ dbf)
{
    int id = blockIdx.x * 256 + threadIdx.x;          // x4 elems
    if (id >= (NVOC * DIM) / 4) return;
    int e = id * 4;
    float4 v = *(const float4*)(dw + e);
    s4v o; o[0] = f2bf(v.x); o[1] = f2bf(v.y); o[2] = f2bf(v.z); o[3] = f2bf(v.w);
    *(s4v*)(dbf + e) = o;
}

// xemb[t*32+b][512] bf16
__global__ __launch_bounds__(256) void embed_k(const int* __restrict__ toks,
                                               const float* __restrict__ emb,
                                               short* __restrict__ xemb)
{
    int id = blockIdx.x * 256 + threadIdx.x;          // x4 elems over 4096*512
    if (id >= (SEQ * BAT * DIM) / 4) return;
    int e  = id * 4;
    int tb = e >> 9;
    int k4 = e & 511;
    int tok = toks[tb];
    float4 v = *(const float4*)(emb + (size_t)tok * DIM + k4);
    s4v o; o[0] = f2bf(v.x); o[1] = f2bf(v.y); o[2] = f2bf(v.z); o[3] = f2bf(v.w);
    *(s4v*)(xemb + e) = o;
}

// zero h buffers [2 layer][2 parity][32][512] + per-block flags
__global__ __launch_bounds__(256) void init_k(short* __restrict__ hbuf,
                                              unsigned* __restrict__ bar)
{
    int id = blockIdx.x * 256 + threadIdx.x;
    if (id < 2 * 2 * BAT * HID) hbuf[id] = 0;
    if (id < NB * 16) bar[id] = 0;
}

// ---------------- persistent recurrence ------------------------------------
// 64 blocks x 256 threads. Block bl: layer = bl>>5, j-slice j0=(bl&31)*16.
// Wave w (=gate) holds rows {w*512 + j0 + 0..15} x K=1024 as hi/lo fragments.
__global__ __launch_bounds__(256, 1) void rnn_k(
    const float* __restrict__ W0, const float* __restrict__ W1,
    const float* __restrict__ U0, const float* __restrict__ U1,
    const float* __restrict__ bias,
    const short* __restrict__ xemb,
    short* __restrict__ hbuf,    // [2][2][32][512] bf16
    short* __restrict__ adec,    // [128*32][512] bf16
    unsigned* __restrict__ bar)  // [64] flags, 64B stride
{
    const int tid   = threadIdx.x;
    const int bl    = blockIdx.x;
    const int layer = bl >> 5;
    const int j0    = (bl & 31) * 16;
    const int w     = tid >> 6;       // wave index == gate index
    const int l     = tid & 63;
    const int lr    = l & 15;
    const int kg    = l >> 4;

    __shared__ short Alds[32][1032];          // 2064B row stride
    __shared__ float gbuf[4][16][33];         // [gate][j][batch(+pad)]

    // --- one-time: load weight slice fp32 -> hi/lo bf16 fragments in VGPRs ---
    const float* Wl = layer ? W1 : W0;
    const float* Ul = layer ? U1 : U0;
    const int gr = w * 512 + j0 + lr;         // gate-row in [0,2048)
    s8v wh[32], wlo[32];
    #pragma unroll
    for (int ks = 0; ks < 32; ++ks) {
        const float* src = (ks < 16)
            ? (Wl + (size_t)gr * 512 + ks * 32 + kg * 8)
            : (Ul + (size_t)gr * 512 + (ks - 16) * 32 + kg * 8);
        float4 va = *(const float4*)src;
        float4 vb = *(const float4*)(src + 4);
        float vv[8] = {va.x, va.y, va.z, va.w, vb.x, vb.y, vb.z, vb.w};
        s8v hi, lo;
        #pragma unroll
        for (int e = 0; e < 8; ++e) {
            short h = f2bf(vv[e]);
            hi[e] = h;
            lo[e] = f2bf(vv[e] - bf2f(h));
        }
        wh[ks] = hi; wlo[ks] = lo;
    }

    // --- epilogue ownership: thread -> (batch eb, j pair ej,ej+1); c in regs -
    const int eb  = tid >> 3;                 // 0..31
    const int ej  = (tid & 7) * 2;            // 0,2,..,14
    const int jg0 = j0 + ej, jg1 = jg0 + 1;
    const float bi0 = bias[jg0],        bi1 = bias[jg1];
    const float bf0 = bias[512 + jg0],  bf1 = bias[512 + jg1];
    const float bg0 = bias[1024 + jg0], bg1 = bias[1024 + jg1];
    const float bo0 = bias[1536 + jg0], bo1 = bias[1536 + jg1];
    float c0 = 0.f, c1 = 0.f;

    short* Hme = hbuf + (size_t)layer * 2 * BAT * HID;  // my layer's dbl-buffer
    const short* H0b = hbuf;                            // layer0 h (both read)

    for (int it = 0; it <= SEQ; ++it) {
        const bool active = (layer == 0) ? (it < SEQ) : (it >= 1);
        const int rp = it & 1, wp = rp ^ 1;

        // xemb half (no cross-block dependence): stage before the wait
        if (active && layer == 0) {
            const short* sA = xemb + (size_t)it * BAT * HID;
            #pragma unroll
            for (int i = 0; i < 8; ++i) {
                int c    = tid + i * 256;     // 2048 chunks of 16B
                int row  = c >> 6;
                int col8 = (c & 63) * 8;
                *(s8v*)&Alds[row][col8] = *(const s8v*)(sA + row * HID + col8);
            }
        }

        // wait for all blocks to have published step it-1
        if (it > 0) {
            if (w == 0) {
                const unsigned* fp = bar + (l << 4);
                while (true) {
                    unsigned v = __hip_atomic_load(fp, __ATOMIC_RELAXED,
                                                   __HIP_MEMORY_SCOPE_AGENT);
                    if (__all((int)(v >= (unsigned)it))) break;
                    __builtin_amdgcn_s_sleep(1);
                }
            }
            __syncthreads();
        }

        if (active) {
            // h halves via coherent 8B loads
            if (layer == 1) {
                const short* sA = H0b + rp * BAT * HID;
                #pragma unroll
                for (int i = 0; i < 16; ++i) {
                    int c    = tid + i * 256; // 4096 chunks of 8B
                    int row  = c >> 7;
                    int col4 = (c & 127) * 4;
                    u64 v = cohload8(sA + row * HID + col4);
                    *(u64*)&Alds[row][col4] = v;
                }
            }
            const short* sB = (layer == 0) ? (H0b + rp * BAT * HID)
                                           : (Hme + rp * BAT * HID);
            #pragma unroll
            for (int i = 0; i < 16; ++i) {
                int c    = tid + i * 256;
                int row  = c >> 7;
                int col4 = (c & 127) * 4;
                u64 v = cohload8(sB + row * HID + col4);
                *(u64*)&Alds[row][512 + col4] = v;
            }
        }
        __syncthreads();

        if (active) {
            f4v a0h, a0l, a1h, a1l;
            a0h[0]=0.f; a0h[1]=0.f; a0h[2]=0.f; a0h[3]=0.f;
            a0l = a0h; a1h = a0h; a1l = a0h;
            #pragma unroll
            for (int ks = 0; ks < 32; ++ks) {
                const int k = ks * 32 + kg * 8;
                s8v a0 = *(const s8v*)&Alds[lr][k];
                s8v a1 = *(const s8v*)&Alds[16 + lr][k];
                a0h = mf16(a0, wh[ks],  a0h);
                a0l = mf16(a0, wlo[ks], a0l);
                a1h = mf16(a1, wh[ks],  a1h);
                a1l = mf16(a1, wlo[ks], a1l);
            }
            #pragma unroll
            for (int r = 0; r < 4; ++r) {
                gbuf[w][lr][kg * 4 + r]      = a0h[r] + a0l[r];
                gbuf[w][lr][16 + kg * 4 + r] = a1h[r] + a1l[r];
            }
        }
        __syncthreads();

        if (active) {
            const int s = (layer == 0) ? it : (it - 1);
            float gi0 = sigm(gbuf[0][ej][eb]     + bi0);
            float gi1 = sigm(gbuf[0][ej + 1][eb] + bi1);
            float gf0 = sigm(gbuf[1][ej][eb]     + bf0);
            float gf1 = sigm(gbuf[1][ej + 1][eb] + bf1);
            float gg0 = tanhf(gbuf[2][ej][eb]     + bg0);
            float gg1 = tanhf(gbuf[2][ej + 1][eb] + bg1);
            float go0 = sigm(gbuf[3][ej][eb]     + bo0);
            float go1 = sigm(gbuf[3][ej + 1][eb] + bo1);
            c0 = gf0 * c0 + gi0 * gg0;
            c1 = gf1 * c1 + gi1 * gg1;
            short h0s = f2bf(go0 * tanhf(c0));
            short h1s = f2bf(go1 * tanhf(c1));
            unsigned hw = (unsigned)(unsigned short)h0s |
                          ((unsigned)(unsigned short)h1s << 16);
            cohstore4(Hme + wp * BAT * HID + eb * HID + jg0, hw);
            if (layer == 1)
                *(unsigned*)(adec + ((size_t)s * BAT + eb) * HID + jg0) = hw;
            (void)s;
        }

        // publish step it: drain my stores, block-sync, one flag store
        if (it < SEQ) {
            asm volatile("s_waitcnt vmcnt(0)" ::: "memory");
            __syncthreads();
            if (tid == 0)
                __hip_atomic_store(bar + (bl << 4), (unsigned)(it + 1),
                                   __ATOMIC_RELAXED, __HIP_MEMORY_SCOPE_AGENT);
        }
    }
}

// ---------------- decoder GEMM ---------------------------------------------
__global__ __launch_bounds__(256) void dec_gemm(
    const short* __restrict__ A,    // [4096][512] bf16
    const short* __restrict__ Bw,   // [32000][512] bf16
    const float* __restrict__ bias, // [32000]
    float* __restrict__ out)        // [4096][32000]
{
    const int nb = blockIdx.x % 250, mb = blockIdx.x / 250;
    const int m0 = mb * 128, n0 = nb * 128;
    __shared__ short Alds[128][40];
    __shared__ short Blds[128][40];
    const int tid = threadIdx.x, l = tid & 63, w = tid >> 6;
    const int wr = w >> 1, wc = w & 1;
    const int lr = l & 15, kg = l >> 4;

    f4v acc[4][4];
    #pragma unroll
    for (int mi = 0; mi < 4; ++mi)
        #pragma unroll
        for (int ni = 0; ni < 4; ++ni) {
            acc[mi][ni][0] = 0.f; acc[mi][ni][1] = 0.f;
            acc[mi][ni][2] = 0.f; acc[mi][ni][3] = 0.f;
        }

    for (int kt = 0; kt < 16; ++kt) {
        #pragma unroll
        for (int i = 0; i < 2; ++i) {
            int c = tid + i * 256;
            int row = c >> 2, q = (c & 3) << 3;
            *(s8v*)&Alds[row][q] = *(const s8v*)(A  + (size_t)(m0 + row) * 512 + kt * 32 + q);
            *(s8v*)&Blds[row][q] = *(const s8v*)(Bw + (size_t)(n0 + row) * 512 + kt * 32 + q);
        }
        __syncthreads();
        s8v af[4], bfr[4];
        #pragma unroll
        for (int i = 0; i < 4; ++i) {
            af[i]  = *(const s8v*)&Alds[wr * 64 + i * 16 + lr][kg * 8];
            bfr[i] = *(const s8v*)&Blds[wc * 64 + i * 16 + lr][kg * 8];
        }
        #pragma unroll
        for (int mi = 0; mi < 4; ++mi)
            #pragma unroll
            for (int ni = 0; ni < 4; ++ni)
                acc[mi][ni] = mf16(af[mi], bfr[ni], acc[mi][ni]);
        __syncthreads();
    }

    #pragma unroll
    for (int mi = 0; mi < 4; ++mi)
        #pragma unroll
        for (int ni = 0; ni < 4; ++ni) {
            int n = n0 + wc * 64 + ni * 16 + lr;
            float bb = bias[n];
            #pragma unroll
            for (int r = 0; r < 4; ++r) {
                int m = m0 + wr * 64 + mi * 16 + kg * 4 + r;
                out[(size_t)m * NVOC + n] = acc[mi][ni][r] + bb;
            }
        }
}

extern "C" void kernel_launch(void* const* d_in, const int* in_sizes, int n_in,
                              void* d_out, int out_size, void* d_ws, size_t ws_size,
                              hipStream_t stream)
{
    const int*   toks = (const int*)d_in[0];
    const float* emb  = (const float*)d_in[1];
    const float* W0   = (const float*)d_in[2];
    const float* W1   = (const float*)d_in[3];
    const float* U0   = (const float*)d_in[4];
    const float* U1   = (const float*)d_in[5];
    const float* bias = (const float*)d_in[6];
    const float* dw   = (const float*)d_in[7];
    const float* db   = (const float*)d_in[8];
    float* out = (float*)d_out;

    char* ws = (char*)d_ws;
    size_t off = 0;
    auto alloc = [&](size_t bytes) -> void* {
        void* p = ws + off;
        off += (bytes + 255) & ~(size_t)255;
        return p;
    };
    short*    dbf  = (short*)alloc((size_t)NVOC * DIM * 2);
    short*    xemb = (short*)alloc((size_t)SEQ * BAT * DIM * 2);
    short*    hbuf = (short*)alloc(2ull * 2 * BAT * HID * 2);
    short*    adec = (short*)alloc((size_t)SEQ * BAT * HID * 2);
    unsigned* bar  = (unsigned*)alloc((size_t)NB * 16 * 4);

    prep_dec<<<(NVOC * DIM / 4 + 255) / 256, 256, 0, stream>>>(dw, dbf);
    embed_k <<<(SEQ * BAT * DIM / 4 + 255) / 256, 256, 0, stream>>>(toks, emb, xemb);
    init_k  <<<256, 256, 0, stream>>>(hbuf, bar);

    rnn_k<<<NB, 256, 0, stream>>>(W0, W1, U0, U1, bias, xemb, hbuf, adec, bar);

    dec_gemm<<<(SEQ * BAT / 128) * (NVOC / 128), 256, 0, stream>>>(adec, dbf, db, out);
}

// Round 6
// 1759.126 us; speedup vs baseline: 3.2916x; 1.0659x over previous
//
#include <hip/hip_runtime.h>
#include <hip/hip_bf16.h>

// ---------------------------------------------------------------------------
// LSTM LM forward on MI355X — round 6.
// Gx0 = xemb @ W0^T precomputed (hi+lo bf16 GEMM). Persistent rnn_k:
// h0 in a 4-slot ring (gives layer0 a provably-safe 2-iteration slack on
// layer1), h1 double-buffered, adjacent single-line arrival counters,
// write-through agent atomics for h, prefetched Gx before the wait.
// Wait rules (iteration it):
//   layer0: cnt0>=32*it (h0 RAW), cnt1>=32*(it-2) (h0-slot WAR, ring depth 4)
//   layer1: cnt0>=32*it (h0 RAW), cnt1>=32*it (own h1 chain RAW+WAR)
// ---------------------------------------------------------------------------

#define NVOC 32000
#define DIM  512
#define HID  512
#define SEQ  128
#define BAT  32
#define NB   64      // blocks in persistent kernel (32 per layer)

typedef short s8v __attribute__((ext_vector_type(8)));
typedef short s4v __attribute__((ext_vector_type(4)));
typedef float f4v __attribute__((ext_vector_type(4)));
typedef unsigned long long u64;

__device__ __forceinline__ short f2bf(float f) {
    unsigned u = __builtin_bit_cast(unsigned, f);
    unsigned r = (u + 0x7fffu + ((u >> 16) & 1u)) >> 16;
    return (short)r;
}
__device__ __forceinline__ float bf2f(short s) {
    unsigned u = ((unsigned)(unsigned short)s) << 16;
    return __builtin_bit_cast(float, u);
}
__device__ __forceinline__ float sigm(float x) { return 1.f / (1.f + __expf(-x)); }

__device__ __forceinline__ f4v mf16(s8v a, s8v b, f4v c) {
    return __builtin_amdgcn_mfma_f32_16x16x32_bf16(a, b, c, 0, 0, 0);
}

// coherent (cross-XCD) 8B load / 4B store, bypassing L1+L2
__device__ __forceinline__ u64 cohload8(const short* p) {
    return __hip_atomic_load((const u64*)p, __ATOMIC_RELAXED,
                             __HIP_MEMORY_SCOPE_AGENT);
}
__device__ __forceinline__ void cohstore4(short* p, unsigned v) {
    __hip_atomic_store((unsigned*)p, v, __ATOMIC_RELAXED,
                       __HIP_MEMORY_SCOPE_AGENT);
}

// ---------------- prep kernels ---------------------------------------------
__global__ __launch_bounds__(256) void prep_dec(const float* __restrict__ dw,
                                                short* __restrict__ dbf)
{
    int id = blockIdx.x * 256 + threadIdx.x;          // x4 elems
    if (id >= (NVOC * DIM) / 4) return;
    int e = id * 4;
    float4 v = *(const float4*)(dw + e);
    s4v o; o[0] = f2bf(v.x); o[1] = f2bf(v.y); o[2] = f2bf(v.z); o[3] = f2bf(v.w);
    *(s4v*)(dbf + e) = o;
}

// split W0 fp32 -> hi/lo bf16 (for the Gx GEMM)
__global__ __launch_bounds__(256) void prep_w0(const float* __restrict__ W0,
                                               short* __restrict__ w0h,
                                               short* __restrict__ w0l)
{
    int id = blockIdx.x * 256 + threadIdx.x;          // 2048*512
    if (id >= 2048 * 512) return;
    float v = W0[id];
    short h = f2bf(v);
    w0h[id] = h;
    w0l[id] = f2bf(v - bf2f(h));
}

// xemb[t*32+b][512] bf16
__global__ __launch_bounds__(256) void embed_k(const int* __restrict__ toks,
                                               const float* __restrict__ emb,
                                               short* __restrict__ xemb)
{
    int id = blockIdx.x * 256 + threadIdx.x;          // x4 elems over 4096*512
    if (id >= (SEQ * BAT * DIM) / 4) return;
    int e  = id * 4;
    int tb = e >> 9;
    int k4 = e & 511;
    int tok = toks[tb];
    float4 v = *(const float4*)(emb + (size_t)tok * DIM + k4);
    s4v o; o[0] = f2bf(v.x); o[1] = f2bf(v.y); o[2] = f2bf(v.z); o[3] = f2bf(v.w);
    *(s4v*)(xemb + e) = o;
}

// zero h rings: h0[4][32][512] + h1[2][32][512] = 98304 shorts; + counters
__global__ __launch_bounds__(256) void init_k(short* __restrict__ hbuf,
                                              unsigned* __restrict__ bar)
{
    int id = blockIdx.x * 256 + threadIdx.x;
    if (id < 6 * BAT * HID) hbuf[id] = 0;
    if (id < 64) bar[id] = 0;                 // bar[0]=cnt0, bar[1]=cnt1
}

// ---------------- Gx0 GEMM: [4096,2048] = xemb @ (W0hi+W0lo)^T, fp32 out ----
__global__ __launch_bounds__(256) void gx_gemm(
    const short* __restrict__ A,    // xemb [4096][512] bf16
    const short* __restrict__ Bh,   // w0hi [2048][512] bf16
    const short* __restrict__ Bl,   // w0lo [2048][512] bf16
    float* __restrict__ out)        // Gx  [4096][2048] fp32
{
    const int nb = blockIdx.x & 15, mb = blockIdx.x >> 4;
    const int m0 = mb * 128, n0 = nb * 128;
    __shared__ short Alds[128][40];
    __shared__ short Bhl[128][40];
    __shared__ short Bll[128][40];
    const int tid = threadIdx.x, l = tid & 63, w = tid >> 6;
    const int wr = w >> 1, wc = w & 1;
    const int lr = l & 15, kg = l >> 4;

    f4v acc[4][4];
    #pragma unroll
    for (int mi = 0; mi < 4; ++mi)
        #pragma unroll
        for (int ni = 0; ni < 4; ++ni) {
            acc[mi][ni][0] = 0.f; acc[mi][ni][1] = 0.f;
            acc[mi][ni][2] = 0.f; acc[mi][ni][3] = 0.f;
        }

    for (int kt = 0; kt < 16; ++kt) {
        #pragma unroll
        for (int i = 0; i < 2; ++i) {
            int c = tid + i * 256;
            int row = c >> 2, q = (c & 3) << 3;
            *(s8v*)&Alds[row][q] = *(const s8v*)(A  + (size_t)(m0 + row) * 512 + kt * 32 + q);
            *(s8v*)&Bhl[row][q]  = *(const s8v*)(Bh + (size_t)(n0 + row) * 512 + kt * 32 + q);
            *(s8v*)&Bll[row][q]  = *(const s8v*)(Bl + (size_t)(n0 + row) * 512 + kt * 32 + q);
        }
        __syncthreads();
        s8v af[4], bhf[4], blf[4];
        #pragma unroll
        for (int i = 0; i < 4; ++i) {
            af[i]  = *(const s8v*)&Alds[wr * 64 + i * 16 + lr][kg * 8];
            bhf[i] = *(const s8v*)&Bhl[wc * 64 + i * 16 + lr][kg * 8];
            blf[i] = *(const s8v*)&Bll[wc * 64 + i * 16 + lr][kg * 8];
        }
        #pragma unroll
        for (int mi = 0; mi < 4; ++mi)
            #pragma unroll
            for (int ni = 0; ni < 4; ++ni) {
                acc[mi][ni] = mf16(af[mi], bhf[ni], acc[mi][ni]);
                acc[mi][ni] = mf16(af[mi], blf[ni], acc[mi][ni]);
            }
        __syncthreads();
    }

    #pragma unroll
    for (int mi = 0; mi < 4; ++mi)
        #pragma unroll
        for (int ni = 0; ni < 4; ++ni) {
            int n = n0 + wc * 64 + ni * 16 + lr;
            #pragma unroll
            for (int r = 0; r < 4; ++r) {
                int m = m0 + wr * 64 + mi * 16 + kg * 4 + r;
                out[(size_t)m * 2048 + n] = acc[mi][ni][r];
            }
        }
}

// ---------------- persistent recurrence ------------------------------------
// 64 blocks x 256 threads. Block bl: layer = bl>>5, j-slice j0=(bl&31)*16.
// h0 ring: slot(it)=it&3, read slot (it-1)&3. h1 ring: write (it-1)&1,
// read (it-2)&1 = it&1.
__global__ __launch_bounds__(256, 1) void rnn_k(
    const float* __restrict__ W1f, const float* __restrict__ U0f,
    const float* __restrict__ U1f,
    const float* __restrict__ bias,
    const float* __restrict__ Gx,   // [4096][2048] fp32
    short* __restrict__ hbuf,       // h0[4][32][512] then h1[2][32][512]
    short* __restrict__ adec,       // [128*32][512] bf16
    unsigned* __restrict__ bar)     // bar[0]=cnt0, bar[1]=cnt1 (same 8B)
{
    const int tid   = threadIdx.x;
    const int bl    = blockIdx.x;
    const int layer = bl >> 5;
    const int j0    = (bl & 31) * 16;
    const int w     = tid >> 6;       // wave index == gate index
    const int l     = tid & 63;
    const int lr    = l & 15;
    const int kg    = l >> 4;

    __shared__ short Alds[32][1032];
    __shared__ float gbuf[4][16][33];

    // --- one-time: weight slice fp32 -> hi/lo bf16 fragments in VGPRs -------
    const int gr = w * 512 + j0 + lr;         // gate-row in [0,2048)
    s8v wh[32], wlo[32];
    if (layer == 0) {
        #pragma unroll
        for (int ks = 0; ks < 16; ++ks) {
            const float* src = U0f + (size_t)gr * 512 + ks * 32 + kg * 8;
            float4 va = *(const float4*)src;
            float4 vb = *(const float4*)(src + 4);
            float vv[8] = {va.x, va.y, va.z, va.w, vb.x, vb.y, vb.z, vb.w};
            s8v hi, lo;
            #pragma unroll
            for (int e = 0; e < 8; ++e) {
                short h = f2bf(vv[e]);
                hi[e] = h; lo[e] = f2bf(vv[e] - bf2f(h));
            }
            wh[ks] = hi; wlo[ks] = lo;
        }
    } else {
        #pragma unroll
        for (int ks = 0; ks < 32; ++ks) {
            const float* src = (ks < 16)
                ? (W1f + (size_t)gr * 512 + ks * 32 + kg * 8)
                : (U1f + (size_t)gr * 512 + (ks - 16) * 32 + kg * 8);
            float4 va = *(const float4*)src;
            float4 vb = *(const float4*)(src + 4);
            float vv[8] = {va.x, va.y, va.z, va.w, vb.x, vb.y, vb.z, vb.w};
            s8v hi, lo;
            #pragma unroll
            for (int e = 0; e < 8; ++e) {
                short h = f2bf(vv[e]);
                hi[e] = h; lo[e] = f2bf(vv[e] - bf2f(h));
            }
            wh[ks] = hi; wlo[ks] = lo;
        }
    }

    // --- epilogue ownership: thread -> (batch eb, j pair ej,ej+1) -----------
    const int eb  = tid >> 3;                 // 0..31
    const int ej  = (tid & 7) * 2;            // 0,2,..,14
    const int jg0 = j0 + ej, jg1 = jg0 + 1;
    const float bi0 = bias[jg0],        bi1 = bias[jg1];
    const float bf0 = bias[512 + jg0],  bf1 = bias[512 + jg1];
    const float bg0 = bias[1024 + jg0], bg1 = bias[1024 + jg1];
    const float bo0 = bias[1536 + jg0], bo1 = bias[1536 + jg1];
    float c0 = 0.f, c1 = 0.f;

    short* h0r = hbuf;                        // [4][32][512]
    short* h1r = hbuf + 4 * BAT * HID;        // [2][32][512]

    for (int it = 0; it <= SEQ; ++it) {
        const bool active = (layer == 0) ? (it < SEQ) : (it >= 1);
        const int s0w = it & 3;               // h0 write slot
        const int s0r = (it + 3) & 3;         // h0 read slot  (it-1)
        const int s1w = (it + 1) & 1;         // h1 write slot (it-1)
        const int s1r = it & 1;               // h1 read slot  (it-2)

        // prefetch Gx slice (layer0) with cached loads BEFORE the wait
        float2 gxv0, gxv1, gxv2, gxv3;
        if (layer == 0 && active) {
            const float* g = Gx + ((size_t)it * BAT + eb) * 2048 + j0 + ej;
            gxv0 = *(const float2*)(g);
            gxv1 = *(const float2*)(g + 512);
            gxv2 = *(const float2*)(g + 1024);
            gxv3 = *(const float2*)(g + 1536);
        }

        if (it > 0) {
            const unsigned t0 = 32u * (unsigned)it;
            const unsigned t1 = (layer == 1) ? 32u * (unsigned)it
                              : (it >= 2 ? 32u * (unsigned)(it - 2) : 0u);
            if (w == 0) {
                while (true) {
                    u64 v = __hip_atomic_load((const u64*)bar, __ATOMIC_RELAXED,
                                              __HIP_MEMORY_SCOPE_AGENT);
                    unsigned a = (unsigned)v;
                    unsigned b = (unsigned)(v >> 32);
                    if (__all((int)(a >= t0 && b >= t1))) break;
                    __builtin_amdgcn_s_sleep(1);
                }
            }
            __syncthreads();
        }

        if (active) {
            if (layer == 0) {
                // stage h0(it-1): 32 rows x 512 shorts = 4096 8B chunks
                const short* s = h0r + s0r * BAT * HID;
                #pragma unroll
                for (int i = 0; i < 16; ++i) {
                    int c    = tid + i * 256;
                    int row  = c >> 7;
                    int col4 = (c & 127) * 4;
                    u64 v = cohload8(s + row * HID + col4);
                    *(u64*)&Alds[row][col4] = v;
                }
            } else {
                const short* sA = h0r + s0r * BAT * HID;      // h0(it-1)
                const short* sB = h1r + s1r * BAT * HID;      // h1(it-2)
                #pragma unroll
                for (int i = 0; i < 16; ++i) {
                    int c    = tid + i * 256;
                    int row  = c >> 7;
                    int col4 = (c & 127) * 4;
                    u64 v = cohload8(sA + row * HID + col4);
                    *(u64*)&Alds[row][col4] = v;
                }
                #pragma unroll
                for (int i = 0; i < 16; ++i) {
                    int c    = tid + i * 256;
                    int row  = c >> 7;
                    int col4 = (c & 127) * 4;
                    u64 v = cohload8(sB + row * HID + col4);
                    *(u64*)&Alds[row][512 + col4] = v;
                }
            }
        }
        __syncthreads();

        if (active) {
            f4v a0h, a0l, a1h, a1l;
            a0h[0]=0.f; a0h[1]=0.f; a0h[2]=0.f; a0h[3]=0.f;
            a0l = a0h; a1h = a0h; a1l = a0h;
            if (layer == 0) {
                #pragma unroll
                for (int ks = 0; ks < 16; ++ks) {
                    const int k = ks * 32 + kg * 8;
                    s8v a0 = *(const s8v*)&Alds[lr][k];
                    s8v a1 = *(const s8v*)&Alds[16 + lr][k];
                    a0h = mf16(a0, wh[ks],  a0h);
                    a0l = mf16(a0, wlo[ks], a0l);
                    a1h = mf16(a1, wh[ks],  a1h);
                    a1l = mf16(a1, wlo[ks], a1l);
                }
            } else {
                #pragma unroll
                for (int ks = 0; ks < 32; ++ks) {
                    const int k = ks * 32 + kg * 8;
                    s8v a0 = *(const s8v*)&Alds[lr][k];
                    s8v a1 = *(const s8v*)&Alds[16 + lr][k];
                    a0h = mf16(a0, wh[ks],  a0h);
                    a0l = mf16(a0, wlo[ks], a0l);
                    a1h = mf16(a1, wh[ks],  a1h);
                    a1l = mf16(a1, wlo[ks], a1l);
                }
            }
            #pragma unroll
            for (int r = 0; r < 4; ++r) {
                gbuf[w][lr][kg * 4 + r]      = a0h[r] + a0l[r];
                gbuf[w][lr][16 + kg * 4 + r] = a1h[r] + a1l[r];
            }
        }
        __syncthreads();

        unsigned hw = 0;
        if (active) {
            float s0 = gbuf[0][ej][eb], s1 = gbuf[0][ej + 1][eb];
            float s2 = gbuf[1][ej][eb], s3 = gbuf[1][ej + 1][eb];
            float s4 = gbuf[2][ej][eb], s5 = gbuf[2][ej + 1][eb];
            float s6 = gbuf[3][ej][eb], s7 = gbuf[3][ej + 1][eb];
            if (layer == 0) {
                s0 += gxv0.x; s1 += gxv0.y;
                s2 += gxv1.x; s3 += gxv1.y;
                s4 += gxv2.x; s5 += gxv2.y;
                s6 += gxv3.x; s7 += gxv3.y;
            }
            float gi0 = sigm(s0 + bi0), gi1 = sigm(s1 + bi1);
            float gf0 = sigm(s2 + bf0), gf1 = sigm(s3 + bf1);
            float gg0 = tanhf(s4 + bg0), gg1 = tanhf(s5 + bg1);
            float go0 = sigm(s6 + bo0), go1 = sigm(s7 + bo1);
            c0 = gf0 * c0 + gi0 * gg0;
            c1 = gf1 * c1 + gi1 * gg1;
            short h0s = f2bf(go0 * tanhf(c0));
            short h1s = f2bf(go1 * tanhf(c1));
            hw = (unsigned)(unsigned short)h0s |
                 ((unsigned)(unsigned short)h1s << 16);
            short* dst = (layer == 0) ? (h0r + s0w * BAT * HID)
                                      : (h1r + s1w * BAT * HID);
            cohstore4(dst + eb * HID + jg0, hw);
        }

        // publish arrival: drain h stores, block-sync, one atomicAdd
        if (it < SEQ) {
            asm volatile("s_waitcnt vmcnt(0)" ::: "memory");
            __syncthreads();
            if (tid == 0)
                __hip_atomic_fetch_add(bar + layer, 1u,
                                       __ATOMIC_RELAXED,
                                       __HIP_MEMORY_SCOPE_AGENT);
        }

        // adec store off the critical path (read only by dec_gemm later)
        if (active && layer == 1)
            *(unsigned*)(adec + ((size_t)(it - 1) * BAT + eb) * HID + jg0) = hw;
    }
}

// ---------------- decoder GEMM ---------------------------------------------
__global__ __launch_bounds__(256) void dec_gemm(
    const short* __restrict__ A,    // [4096][512] bf16
    const short* __restrict__ Bw,   // [32000][512] bf16
    const float* __restrict__ bias, // [32000]
    float* __restrict__ out)        // [4096][32000]
{
    const int nb = blockIdx.x % 250, mb = blockIdx.x / 250;
    const int m0 = mb * 128, n0 = nb * 128;
    __shared__ short Alds[128][40];
    __shared__ short Blds[128][40];
    const int tid = threadIdx.x, l = tid & 63, w = tid >> 6;
    const int wr = w >> 1, wc = w & 1;
    const int lr = l & 15, kg = l >> 4;

    f4v acc[4][4];
    #pragma unroll
    for (int mi = 0; mi < 4; ++mi)
        #pragma unroll
        for (int ni = 0; ni < 4; ++ni) {
            acc[mi][ni][0] = 0.f; acc[mi][ni][1] = 0.f;
            acc[mi][ni][2] = 0.f; acc[mi][ni][3] = 0.f;
        }

    for (int kt = 0; kt < 16; ++kt) {
        #pragma unroll
        for (int i = 0; i < 2; ++i) {
            int c = tid + i * 256;
            int row = c >> 2, q = (c & 3) << 3;
            *(s8v*)&Alds[row][q] = *(const s8v*)(A  + (size_t)(m0 + row) * 512 + kt * 32 + q);
            *(s8v*)&Blds[row][q] = *(const s8v*)(Bw + (size_t)(n0 + row) * 512 + kt * 32 + q);
        }
        __syncthreads();
        s8v af[4], bfr[4];
        #pragma unroll
        for (int i = 0; i < 4; ++i) {
            af[i]  = *(const s8v*)&Alds[wr * 64 + i * 16 + lr][kg * 8];
            bfr[i] = *(const s8v*)&Blds[wc * 64 + i * 16 + lr][kg * 8];
        }
        #pragma unroll
        for (int mi = 0; mi < 4; ++mi)
            #pragma unroll
            for (int ni = 0; ni < 4; ++ni)
                acc[mi][ni] = mf16(af[mi], bfr[ni], acc[mi][ni]);
        __syncthreads();
    }

    #pragma unroll
    for (int mi = 0; mi < 4; ++mi)
        #pragma unroll
        for (int ni = 0; ni < 4; ++ni) {
            int n = n0 + wc * 64 + ni * 16 + lr;
            float bb = bias[n];
            #pragma unroll
            for (int r = 0; r < 4; ++r) {
                int m = m0 + wr * 64 + mi * 16 + kg * 4 + r;
                out[(size_t)m * NVOC + n] = acc[mi][ni][r] + bb;
            }
        }
}

extern "C" void kernel_launch(void* const* d_in, const int* in_sizes, int n_in,
                              void* d_out, int out_size, void* d_ws, size_t ws_size,
                              hipStream_t stream)
{
    const int*   toks = (const int*)d_in[0];
    const float* emb  = (const float*)d_in[1];
    const float* W0   = (const float*)d_in[2];
    const float* W1   = (const float*)d_in[3];
    const float* U0   = (const float*)d_in[4];
    const float* U1   = (const float*)d_in[5];
    const float* bias = (const float*)d_in[6];
    const float* dw   = (const float*)d_in[7];
    const float* db   = (const float*)d_in[8];
    float* out = (float*)d_out;

    char* ws = (char*)d_ws;
    size_t off = 0;
    auto alloc = [&](size_t bytes) -> void* {
        void* p = ws + off;
        off += (bytes + 255) & ~(size_t)255;
        return p;
    };
    short*    dbf  = (short*)alloc((size_t)NVOC * DIM * 2);
    short*    xemb = (short*)alloc((size_t)SEQ * BAT * DIM * 2);
    short*    w0h  = (short*)alloc(2048ull * 512 * 2);
    short*    w0l  = (short*)alloc(2048ull * 512 * 2);
    float*    Gx   = (float*)alloc((size_t)SEQ * BAT * 2048 * 4);
    short*    hbuf = (short*)alloc(6ull * BAT * HID * 2);
    short*    adec = (short*)alloc((size_t)SEQ * BAT * HID * 2);
    unsigned* bar  = (unsigned*)alloc(256);

    prep_dec<<<(NVOC * DIM / 4 + 255) / 256, 256, 0, stream>>>(dw, dbf);
    prep_w0 <<<(2048 * 512 + 255) / 256, 256, 0, stream>>>(W0, w0h, w0l);
    embed_k <<<(SEQ * BAT * DIM / 4 + 255) / 256, 256, 0, stream>>>(toks, emb, xemb);
    init_k  <<<384, 256, 0, stream>>>(hbuf, bar);

    gx_gemm<<<32 * 16, 256, 0, stream>>>(xemb, w0h, w0l, Gx);

    rnn_k<<<NB, 256, 0, stream>>>(W1, U0, U1, bias, Gx, hbuf, adec, bar);

    dec_gemm<<<(SEQ * BAT / 128) * (NVOC / 128), 256, 0, stream>>>(adec, dbf, db, out);
}

// Round 7
// 1280.324 us; speedup vs baseline: 4.5225x; 1.3740x over previous
//
#include <hip/hip_runtime.h>
#include <hip/hip_bf16.h>

// ---------------------------------------------------------------------------
// LSTM LM forward on MI355X — round 7.
// Same sync design as round 6 (h0 4-slot ring, h1 2-slot, adjacent counters,
// write-through agent atomics, Gx hoist). NEW: rnn_k uses 512 threads =
// 8 waves per block; wave (gate, K-half) holds only 128 VGPRs of weight
// fragments (layer1) -> no scratch spill in the MFMA loop. K-half partial
// sums reduced through LDS in the epilogue.
// ---------------------------------------------------------------------------

#define NVOC 32000
#define DIM  512
#define HID  512
#define SEQ  128
#define BAT  32
#define NB   64      // blocks in persistent kernel (32 per layer)

typedef short s8v __attribute__((ext_vector_type(8)));
typedef short s4v __attribute__((ext_vector_type(4)));
typedef float f4v __attribute__((ext_vector_type(4)));
typedef unsigned long long u64;

__device__ __forceinline__ short f2bf(float f) {
    unsigned u = __builtin_bit_cast(unsigned, f);
    unsigned r = (u + 0x7fffu + ((u >> 16) & 1u)) >> 16;
    return (short)r;
}
__device__ __forceinline__ float bf2f(short s) {
    unsigned u = ((unsigned)(unsigned short)s) << 16;
    return __builtin_bit_cast(float, u);
}
__device__ __forceinline__ float sigm(float x) { return 1.f / (1.f + __expf(-x)); }

__device__ __forceinline__ f4v mf16(s8v a, s8v b, f4v c) {
    return __builtin_amdgcn_mfma_f32_16x16x32_bf16(a, b, c, 0, 0, 0);
}

// coherent (cross-XCD) loads/stores, bypassing L1+L2
__device__ __forceinline__ u64 cohload8(const short* p) {
    return __hip_atomic_load((const u64*)p, __ATOMIC_RELAXED,
                             __HIP_MEMORY_SCOPE_AGENT);
}
__device__ __forceinline__ void cohstore2(short* p, unsigned short v) {
    __hip_atomic_store((unsigned short*)p, v, __ATOMIC_RELAXED,
                       __HIP_MEMORY_SCOPE_AGENT);
}

// ---------------- prep kernels ---------------------------------------------
__global__ __launch_bounds__(256) void prep_dec(const float* __restrict__ dw,
                                                short* __restrict__ dbf)
{
    int id = blockIdx.x * 256 + threadIdx.x;          // x4 elems
    if (id >= (NVOC * DIM) / 4) return;
    int e = id * 4;
    float4 v = *(const float4*)(dw + e);
    s4v o; o[0] = f2bf(v.x); o[1] = f2bf(v.y); o[2] = f2bf(v.z); o[3] = f2bf(v.w);
    *(s4v*)(dbf + e) = o;
}

// split W0 fp32 -> hi/lo bf16 (for the Gx GEMM)
__global__ __launch_bounds__(256) void prep_w0(const float* __restrict__ W0,
                                               short* __restrict__ w0h,
                                               short* __restrict__ w0l)
{
    int id = blockIdx.x * 256 + threadIdx.x;          // 2048*512
    if (id >= 2048 * 512) return;
    float v = W0[id];
    short h = f2bf(v);
    w0h[id] = h;
    w0l[id] = f2bf(v - bf2f(h));
}

// xemb[t*32+b][512] bf16
__global__ __launch_bounds__(256) void embed_k(const int* __restrict__ toks,
                                               const float* __restrict__ emb,
                                               short* __restrict__ xemb)
{
    int id = blockIdx.x * 256 + threadIdx.x;          // x4 elems over 4096*512
    if (id >= (SEQ * BAT * DIM) / 4) return;
    int e  = id * 4;
    int tb = e >> 9;
    int k4 = e & 511;
    int tok = toks[tb];
    float4 v = *(const float4*)(emb + (size_t)tok * DIM + k4);
    s4v o; o[0] = f2bf(v.x); o[1] = f2bf(v.y); o[2] = f2bf(v.z); o[3] = f2bf(v.w);
    *(s4v*)(xemb + e) = o;
}

// zero h rings: h0[4][32][512] + h1[2][32][512]; + counters
__global__ __launch_bounds__(256) void init_k(short* __restrict__ hbuf,
                                              unsigned* __restrict__ bar)
{
    int id = blockIdx.x * 256 + threadIdx.x;
    if (id < 6 * BAT * HID) hbuf[id] = 0;
    if (id < 64) bar[id] = 0;                 // bar[0]=cnt0, bar[1]=cnt1
}

// ---------------- Gx0 GEMM: [4096,2048] = xemb @ (W0hi+W0lo)^T, fp32 out ----
__global__ __launch_bounds__(256) void gx_gemm(
    const short* __restrict__ A,    // xemb [4096][512] bf16
    const short* __restrict__ Bh,   // w0hi [2048][512] bf16
    const short* __restrict__ Bl,   // w0lo [2048][512] bf16
    float* __restrict__ out)        // Gx  [4096][2048] fp32
{
    const int nb = blockIdx.x & 15, mb = blockIdx.x >> 4;
    const int m0 = mb * 128, n0 = nb * 128;
    __shared__ short Alds[128][40];
    __shared__ short Bhl[128][40];
    __shared__ short Bll[128][40];
    const int tid = threadIdx.x, l = tid & 63, w = tid >> 6;
    const int wr = w >> 1, wc = w & 1;
    const int lr = l & 15, kg = l >> 4;

    f4v acc[4][4];
    #pragma unroll
    for (int mi = 0; mi < 4; ++mi)
        #pragma unroll
        for (int ni = 0; ni < 4; ++ni) {
            acc[mi][ni][0] = 0.f; acc[mi][ni][1] = 0.f;
            acc[mi][ni][2] = 0.f; acc[mi][ni][3] = 0.f;
        }

    for (int kt = 0; kt < 16; ++kt) {
        #pragma unroll
        for (int i = 0; i < 2; ++i) {
            int c = tid + i * 256;
            int row = c >> 2, q = (c & 3) << 3;
            *(s8v*)&Alds[row][q] = *(const s8v*)(A  + (size_t)(m0 + row) * 512 + kt * 32 + q);
            *(s8v*)&Bhl[row][q]  = *(const s8v*)(Bh + (size_t)(n0 + row) * 512 + kt * 32 + q);
            *(s8v*)&Bll[row][q]  = *(const s8v*)(Bl + (size_t)(n0 + row) * 512 + kt * 32 + q);
        }
        __syncthreads();
        s8v af[4], bhf[4], blf[4];
        #pragma unroll
        for (int i = 0; i < 4; ++i) {
            af[i]  = *(const s8v*)&Alds[wr * 64 + i * 16 + lr][kg * 8];
            bhf[i] = *(const s8v*)&Bhl[wc * 64 + i * 16 + lr][kg * 8];
            blf[i] = *(const s8v*)&Bll[wc * 64 + i * 16 + lr][kg * 8];
        }
        #pragma unroll
        for (int mi = 0; mi < 4; ++mi)
            #pragma unroll
            for (int ni = 0; ni < 4; ++ni) {
                acc[mi][ni] = mf16(af[mi], bhf[ni], acc[mi][ni]);
                acc[mi][ni] = mf16(af[mi], blf[ni], acc[mi][ni]);
            }
        __syncthreads();
    }

    #pragma unroll
    for (int mi = 0; mi < 4; ++mi)
        #pragma unroll
        for (int ni = 0; ni < 4; ++ni) {
            int n = n0 + wc * 64 + ni * 16 + lr;
            #pragma unroll
            for (int r = 0; r < 4; ++r) {
                int m = m0 + wr * 64 + mi * 16 + kg * 4 + r;
                out[(size_t)m * 2048 + n] = acc[mi][ni][r];
            }
        }
}

// ---------------- persistent recurrence ------------------------------------
// 64 blocks x 512 threads (8 waves). Block bl: layer=bl>>5, j0=(bl&31)*16.
// Wave w2: gate g = w2&3, K-half kh = w2>>2. Wave holds 16 rows x K/2 as
// hi/lo fragments (layer1: 128 VGPR, layer0: 64). Partials in gbuf[kh].
// h0 ring: write it&3, read (it-1)&3. h1: write (it-1)&1, read (it-2)&1.
// Waits (iteration it):
//   layer0: cnt0>=32*it, cnt1>=32*(it-2)   (ring-depth-4 WAR slack)
//   layer1: cnt0>=32*it, cnt1>=32*it
__global__ __launch_bounds__(512, 1) void rnn_k(
    const float* __restrict__ W1f, const float* __restrict__ U0f,
    const float* __restrict__ U1f,
    const float* __restrict__ bias,
    const float* __restrict__ Gx,   // [4096][2048] fp32
    short* __restrict__ hbuf,       // h0[4][32][512] then h1[2][32][512]
    short* __restrict__ adec,       // [128*32][512] bf16
    unsigned* __restrict__ bar)     // bar[0]=cnt0, bar[1]=cnt1 (same 8B)
{
    const int tid   = threadIdx.x;
    const int bl    = blockIdx.x;
    const int layer = bl >> 5;
    const int j0    = (bl & 31) * 16;
    const int w2    = tid >> 6;       // 0..7
    const int g     = w2 & 3;         // gate
    const int kh    = w2 >> 2;        // K-half
    const int l     = tid & 63;
    const int lr    = l & 15;
    const int kg    = l >> 4;

    __shared__ short Alds[32][1032];
    __shared__ float gbuf[2][4][16][33];      // [kh][gate][j][batch(+pad)]

    // --- one-time: weight slice fp32 -> hi/lo bf16 fragments in VGPRs -------
    const int gr = g * 512 + j0 + lr;         // gate-row in [0,2048)
    s8v wh[16], wlo[16];
    if (layer == 0) {
        // U0 only, K=512; this wave's half: cols [kh*256, kh*256+256)
        #pragma unroll
        for (int ks = 0; ks < 8; ++ks) {
            const float* src = U0f + (size_t)gr * 512 + kh * 256 + ks * 32 + kg * 8;
            float4 va = *(const float4*)src;
            float4 vb = *(const float4*)(src + 4);
            float vv[8] = {va.x, va.y, va.z, va.w, vb.x, vb.y, vb.z, vb.w};
            s8v hi, lo;
            #pragma unroll
            for (int e = 0; e < 8; ++e) {
                short h = f2bf(vv[e]);
                hi[e] = h; lo[e] = f2bf(vv[e] - bf2f(h));
            }
            wh[ks] = hi; wlo[ks] = lo;
        }
    } else {
        // [W1 | U1], K=1024; kh=0 -> W1 (vs h0), kh=1 -> U1 (vs h1)
        const float* base = kh ? U1f : W1f;
        #pragma unroll
        for (int ks = 0; ks < 16; ++ks) {
            const float* src = base + (size_t)gr * 512 + ks * 32 + kg * 8;
            float4 va = *(const float4*)src;
            float4 vb = *(const float4*)(src + 4);
            float vv[8] = {va.x, va.y, va.z, va.w, vb.x, vb.y, vb.z, vb.w};
            s8v hi, lo;
            #pragma unroll
            for (int e = 0; e < 8; ++e) {
                short h = f2bf(vv[e]);
                hi[e] = h; lo[e] = f2bf(vv[e] - bf2f(h));
            }
            wh[ks] = hi; wlo[ks] = lo;
        }
    }

    // --- epilogue ownership: thread -> (batch eb, single j = j0+ej) ---------
    const int eb = tid >> 4;                  // 0..31
    const int ej = tid & 15;                  // 0..15
    const int jj = j0 + ej;
    const float bi = bias[jj];
    const float bf_ = bias[512 + jj];
    const float bg = bias[1024 + jj];
    const float bo = bias[1536 + jj];
    float cst = 0.f;

    short* h0r = hbuf;                        // [4][32][512]
    short* h1r = hbuf + 4 * BAT * HID;        // [2][32][512]

    for (int it = 0; it <= SEQ; ++it) {
        const bool active = (layer == 0) ? (it < SEQ) : (it >= 1);
        const int s0w = it & 3;               // h0 write slot
        const int s0r = (it + 3) & 3;         // h0 read slot  (it-1)
        const int s1w = (it + 1) & 1;         // h1 write slot (it-1)
        const int s1r = it & 1;               // h1 read slot  (it-2)

        // prefetch Gx (layer0): 4 gate pre-activations for (eb, jj)
        float gx0 = 0.f, gx1 = 0.f, gx2 = 0.f, gx3 = 0.f;
        if (layer == 0 && active) {
            const float* gp = Gx + ((size_t)it * BAT + eb) * 2048 + jj;
            gx0 = gp[0]; gx1 = gp[512]; gx2 = gp[1024]; gx3 = gp[1536];
        }

        if (it > 0) {
            const unsigned t0 = 32u * (unsigned)it;
            const unsigned t1 = (layer == 1) ? 32u * (unsigned)it
                              : (it >= 2 ? 32u * (unsigned)(it - 2) : 0u);
            if (w2 == 0) {
                while (true) {
                    u64 v = __hip_atomic_load((const u64*)bar, __ATOMIC_RELAXED,
                                              __HIP_MEMORY_SCOPE_AGENT);
                    unsigned a = (unsigned)v;
                    unsigned b = (unsigned)(v >> 32);
                    if (__all((int)(a >= t0 && b >= t1))) break;
                    __builtin_amdgcn_s_sleep(1);
                }
            }
            __syncthreads();
        }

        if (active) {
            if (layer == 0) {
                // stage h0(it-1): 4096 8B chunks over 512 threads
                const short* s = h0r + s0r * BAT * HID;
                #pragma unroll
                for (int i = 0; i < 8; ++i) {
                    int c    = tid + i * 512;
                    int row  = c >> 7;
                    int col4 = (c & 127) * 4;
                    u64 v = cohload8(s + row * HID + col4);
                    *(u64*)&Alds[row][col4] = v;
                }
            } else {
                const short* sA = h0r + s0r * BAT * HID;      // h0(it-1)
                const short* sB = h1r + s1r * BAT * HID;      // h1(it-2)
                #pragma unroll
                for (int i = 0; i < 8; ++i) {
                    int c    = tid + i * 512;
                    int row  = c >> 7;
                    int col4 = (c & 127) * 4;
                    u64 v = cohload8(sA + row * HID + col4);
                    *(u64*)&Alds[row][col4] = v;
                }
                #pragma unroll
                for (int i = 0; i < 8; ++i) {
                    int c    = tid + i * 512;
                    int row  = c >> 7;
                    int col4 = (c & 127) * 4;
                    u64 v = cohload8(sB + row * HID + col4);
                    *(u64*)&Alds[row][512 + col4] = v;
                }
            }
        }
        __syncthreads();

        if (active) {
            f4v a0h, a0l, a1h, a1l;
            a0h[0]=0.f; a0h[1]=0.f; a0h[2]=0.f; a0h[3]=0.f;
            a0l = a0h; a1h = a0h; a1l = a0h;
            if (layer == 0) {
                #pragma unroll
                for (int ks = 0; ks < 8; ++ks) {
                    const int k = kh * 256 + ks * 32 + kg * 8;
                    s8v a0 = *(const s8v*)&Alds[lr][k];
                    s8v a1 = *(const s8v*)&Alds[16 + lr][k];
                    a0h = mf16(a0, wh[ks],  a0h);
                    a0l = mf16(a0, wlo[ks], a0l);
                    a1h = mf16(a1, wh[ks],  a1h);
                    a1l = mf16(a1, wlo[ks], a1l);
                }
            } else {
                #pragma unroll
                for (int ks = 0; ks < 16; ++ks) {
                    const int k = kh * 512 + ks * 32 + kg * 8;
                    s8v a0 = *(const s8v*)&Alds[lr][k];
                    s8v a1 = *(const s8v*)&Alds[16 + lr][k];
                    a0h = mf16(a0, wh[ks],  a0h);
                    a0l = mf16(a0, wlo[ks], a0l);
                    a1h = mf16(a1, wh[ks],  a1h);
                    a1l = mf16(a1, wlo[ks], a1l);
                }
            }
            #pragma unroll
            for (int r = 0; r < 4; ++r) {
                gbuf[kh][g][lr][kg * 4 + r]      = a0h[r] + a0l[r];
                gbuf[kh][g][lr][16 + kg * 4 + r] = a1h[r] + a1l[r];
            }
        }
        __syncthreads();

        unsigned short hs = 0;
        if (active) {
            float si = gbuf[0][0][ej][eb] + gbuf[1][0][ej][eb];
            float sf = gbuf[0][1][ej][eb] + gbuf[1][1][ej][eb];
            float sg = gbuf[0][2][ej][eb] + gbuf[1][2][ej][eb];
            float so = gbuf[0][3][ej][eb] + gbuf[1][3][ej][eb];
            if (layer == 0) { si += gx0; sf += gx1; sg += gx2; so += gx3; }
            float gi = sigm(si + bi);
            float gf = sigm(sf + bf_);
            float gg = tanhf(sg + bg);
            float go = sigm(so + bo);
            cst = gf * cst + gi * gg;
            hs = (unsigned short)f2bf(go * tanhf(cst));
            short* dst = (layer == 0) ? (h0r + s0w * BAT * HID)
                                      : (h1r + s1w * BAT * HID);
            cohstore2(dst + eb * HID + jj, hs);
        }

        // publish arrival: drain h stores, block-sync, one atomicAdd
        if (it < SEQ) {
            asm volatile("s_waitcnt vmcnt(0)" ::: "memory");
            __syncthreads();
            if (tid == 0)
                __hip_atomic_fetch_add(bar + layer, 1u,
                                       __ATOMIC_RELAXED,
                                       __HIP_MEMORY_SCOPE_AGENT);
        }

        // adec store off the critical path (read only by dec_gemm later)
        if (active && layer == 1)
            adec[((size_t)(it - 1) * BAT + eb) * HID + jj] = (short)hs;
    }
}

// ---------------- decoder GEMM ---------------------------------------------
__global__ __launch_bounds__(256) void dec_gemm(
    const short* __restrict__ A,    // [4096][512] bf16
    const short* __restrict__ Bw,   // [32000][512] bf16
    const float* __restrict__ bias, // [32000]
    float* __restrict__ out)        // [4096][32000]
{
    const int nb = blockIdx.x % 250, mb = blockIdx.x / 250;
    const int m0 = mb * 128, n0 = nb * 128;
    __shared__ short Alds[128][40];
    __shared__ short Blds[128][40];
    const int tid = threadIdx.x, l = tid & 63, w = tid >> 6;
    const int wr = w >> 1, wc = w & 1;
    const int lr = l & 15, kg = l >> 4;

    f4v acc[4][4];
    #pragma unroll
    for (int mi = 0; mi < 4; ++mi)
        #pragma unroll
        for (int ni = 0; ni < 4; ++ni) {
            acc[mi][ni][0] = 0.f; acc[mi][ni][1] = 0.f;
            acc[mi][ni][2] = 0.f; acc[mi][ni][3] = 0.f;
        }

    for (int kt = 0; kt < 16; ++kt) {
        #pragma unroll
        for (int i = 0; i < 2; ++i) {
            int c = tid + i * 256;
            int row = c >> 2, q = (c & 3) << 3;
            *(s8v*)&Alds[row][q] = *(const s8v*)(A  + (size_t)(m0 + row) * 512 + kt * 32 + q);
            *(s8v*)&Blds[row][q] = *(const s8v*)(Bw + (size_t)(n0 + row) * 512 + kt * 32 + q);
        }
        __syncthreads();
        s8v af[4], bfr[4];
        #pragma unroll
        for (int i = 0; i < 4; ++i) {
            af[i]  = *(const s8v*)&Alds[wr * 64 + i * 16 + lr][kg * 8];
            bfr[i] = *(const s8v*)&Blds[wc * 64 + i * 16 + lr][kg * 8];
        }
        #pragma unroll
        for (int mi = 0; mi < 4; ++mi)
            #pragma unroll
            for (int ni = 0; ni < 4; ++ni)
                acc[mi][ni] = mf16(af[mi], bfr[ni], acc[mi][ni]);
        __syncthreads();
    }

    #pragma unroll
    for (int mi = 0; mi < 4; ++mi)
        #pragma unroll
        for (int ni = 0; ni < 4; ++ni) {
            int n = n0 + wc * 64 + ni * 16 + lr;
            float bb = bias[n];
            #pragma unroll
            for (int r = 0; r < 4; ++r) {
                int m = m0 + wr * 64 + mi * 16 + kg * 4 + r;
                out[(size_t)m * NVOC + n] = acc[mi][ni][r] + bb;
            }
        }
}

extern "C" void kernel_launch(void* const* d_in, const int* in_sizes, int n_in,
                              void* d_out, int out_size, void* d_ws, size_t ws_size,
                              hipStream_t stream)
{
    const int*   toks = (const int*)d_in[0];
    const float* emb  = (const float*)d_in[1];
    const float* W0   = (const float*)d_in[2];
    const float* W1   = (const float*)d_in[3];
    const float* U0   = (const float*)d_in[4];
    const float* U1   = (const float*)d_in[5];
    const float* bias = (const float*)d_in[6];
    const float* dw   = (const float*)d_in[7];
    const float* db   = (const float*)d_in[8];
    float* out = (float*)d_out;

    char* ws = (char*)d_ws;
    size_t off = 0;
    auto alloc = [&](size_t bytes) -> void* {
        void* p = ws + off;
        off += (bytes + 255) & ~(size_t)255;
        return p;
    };
    short*    dbf  = (short*)alloc((size_t)NVOC * DIM * 2);
    short*    xemb = (short*)alloc((size_t)SEQ * BAT * DIM * 2);
    short*    w0h  = (short*)alloc(2048ull * 512 * 2);
    short*    w0l  = (short*)alloc(2048ull * 512 * 2);
    float*    Gx   = (float*)alloc((size_t)SEQ * BAT * 2048 * 4);
    short*    hbuf = (short*)alloc(6ull * BAT * HID * 2);
    short*    adec = (short*)alloc((size_t)SEQ * BAT * HID * 2);
    unsigned* bar  = (unsigned*)alloc(256);

    prep_dec<<<(NVOC * DIM / 4 + 255) / 256, 256, 0, stream>>>(dw, dbf);
    prep_w0 <<<(2048 * 512 + 255) / 256, 256, 0, stream>>>(W0, w0h, w0l);
    embed_k <<<(SEQ * BAT * DIM / 4 + 255) / 256, 256, 0, stream>>>(toks, emb, xemb);
    init_k  <<<384, 256, 0, stream>>>(hbuf, bar);

    gx_gemm<<<32 * 16, 256, 0, stream>>>(xemb, w0h, w0l, Gx);

    rnn_k<<<NB, 512, 0, stream>>>(W1, U0, U1, bias, Gx, hbuf, adec, bar);

    dec_gemm<<<(SEQ * BAT / 128) * (NVOC / 128), 256, 0, stream>>>(adec, dbf, db, out);
}

// Round 8
// 1135.473 us; speedup vs baseline: 5.0995x; 1.1276x over previous
//
#include <hip/hip_runtime.h>
#include <hip/hip_bf16.h>

// ---------------------------------------------------------------------------
// LSTM LM forward on MI355X — round 8.
// Round-7 compute structure (8 waves/block, K-split wave pairs, 128 VGPR
// weight fragments). NEW sync path:
//   - packed per-block flag STORES (no atomic RMW): bar[0..31]=L0, [32..63]=L1
//   - layer1 split waits: stage h0-half before the flags1 wait
//   - layer0 WAR gate moved after compute; h0 ring deepened to 8 slots
// Wait rules (iteration it):
//   L0: flags0>=it before staging h0(it-1); flags1>=it-6 before storing h0(it)
//   L1: flags0>=it before staging h0(it-1); flags1>=it before staging h1(it-2)
// ---------------------------------------------------------------------------

#define NVOC 32000
#define DIM  512
#define HID  512
#define SEQ  128
#define BAT  32
#define NB   64      // blocks in persistent kernel (32 per layer)

typedef short s8v __attribute__((ext_vector_type(8)));
typedef short s4v __attribute__((ext_vector_type(4)));
typedef float f4v __attribute__((ext_vector_type(4)));
typedef unsigned long long u64;

__device__ __forceinline__ short f2bf(float f) {
    unsigned u = __builtin_bit_cast(unsigned, f);
    unsigned r = (u + 0x7fffu + ((u >> 16) & 1u)) >> 16;
    return (short)r;
}
__device__ __forceinline__ float bf2f(short s) {
    unsigned u = ((unsigned)(unsigned short)s) << 16;
    return __builtin_bit_cast(float, u);
}
__device__ __forceinline__ float sigm(float x) { return 1.f / (1.f + __expf(-x)); }

__device__ __forceinline__ f4v mf16(s8v a, s8v b, f4v c) {
    return __builtin_amdgcn_mfma_f32_16x16x32_bf16(a, b, c, 0, 0, 0);
}

// coherent (cross-XCD) loads/stores, bypassing L1+L2
__device__ __forceinline__ u64 cohload8(const short* p) {
    return __hip_atomic_load((const u64*)p, __ATOMIC_RELAXED,
                             __HIP_MEMORY_SCOPE_AGENT);
}
__device__ __forceinline__ void cohstore2(short* p, unsigned short v) {
    __hip_atomic_store((unsigned short*)p, v, __ATOMIC_RELAXED,
                       __HIP_MEMORY_SCOPE_AGENT);
}

// poll (one wave): lane<32 checks flags0[l]>=tA, lane>=32 checks flags1[l-32]>=tB
__device__ __forceinline__ void pollwait(const unsigned* bar, int l,
                                         unsigned tA, unsigned tB) {
    const unsigned* fp = bar + l;
    const unsigned tgt = (l < 32) ? tA : tB;
    while (true) {
        unsigned v = __hip_atomic_load(fp, __ATOMIC_RELAXED,
                                       __HIP_MEMORY_SCOPE_AGENT);
        if (__all((int)(v >= tgt))) break;
        __builtin_amdgcn_s_sleep(1);
    }
}

// ---------------- prep kernels ---------------------------------------------
__global__ __launch_bounds__(256) void prep_dec(const float* __restrict__ dw,
                                                short* __restrict__ dbf)
{
    int id = blockIdx.x * 256 + threadIdx.x;          // x4 elems
    if (id >= (NVOC * DIM) / 4) return;
    int e = id * 4;
    float4 v = *(const float4*)(dw + e);
    s4v o; o[0] = f2bf(v.x); o[1] = f2bf(v.y); o[2] = f2bf(v.z); o[3] = f2bf(v.w);
    *(s4v*)(dbf + e) = o;
}

// split W0 fp32 -> hi/lo bf16 (for the Gx GEMM)
__global__ __launch_bounds__(256) void prep_w0(const float* __restrict__ W0,
                                               short* __restrict__ w0h,
                                               short* __restrict__ w0l)
{
    int id = blockIdx.x * 256 + threadIdx.x;          // 2048*512
    if (id >= 2048 * 512) return;
    float v = W0[id];
    short h = f2bf(v);
    w0h[id] = h;
    w0l[id] = f2bf(v - bf2f(h));
}

// xemb[t*32+b][512] bf16
__global__ __launch_bounds__(256) void embed_k(const int* __restrict__ toks,
                                               const float* __restrict__ emb,
                                               short* __restrict__ xemb)
{
    int id = blockIdx.x * 256 + threadIdx.x;          // x4 elems over 4096*512
    if (id >= (SEQ * BAT * DIM) / 4) return;
    int e  = id * 4;
    int tb = e >> 9;
    int k4 = e & 511;
    int tok = toks[tb];
    float4 v = *(const float4*)(emb + (size_t)tok * DIM + k4);
    s4v o; o[0] = f2bf(v.x); o[1] = f2bf(v.y); o[2] = f2bf(v.z); o[3] = f2bf(v.w);
    *(s4v*)(xemb + e) = o;
}

// zero h rings: h0[8][32][512] + h1[2][32][512] = 10 slots; + flags
__global__ __launch_bounds__(256) void init_k(short* __restrict__ hbuf,
                                              unsigned* __restrict__ bar)
{
    int id = blockIdx.x * 256 + threadIdx.x;
    if (id < 10 * BAT * HID) hbuf[id] = 0;
    if (id < 64) bar[id] = 0;
}

// ---------------- Gx0 GEMM: [4096,2048] = xemb @ (W0hi+W0lo)^T, fp32 out ----
__global__ __launch_bounds__(256) void gx_gemm(
    const short* __restrict__ A,    // xemb [4096][512] bf16
    const short* __restrict__ Bh,   // w0hi [2048][512] bf16
    const short* __restrict__ Bl,   // w0lo [2048][512] bf16
    float* __restrict__ out)        // Gx  [4096][2048] fp32
{
    const int nb = blockIdx.x & 15, mb = blockIdx.x >> 4;
    const int m0 = mb * 128, n0 = nb * 128;
    __shared__ short Alds[128][40];
    __shared__ short Bhl[128][40];
    __shared__ short Bll[128][40];
    const int tid = threadIdx.x, l = tid & 63, w = tid >> 6;
    const int wr = w >> 1, wc = w & 1;
    const int lr = l & 15, kg = l >> 4;

    f4v acc[4][4];
    #pragma unroll
    for (int mi = 0; mi < 4; ++mi)
        #pragma unroll
        for (int ni = 0; ni < 4; ++ni) {
            acc[mi][ni][0] = 0.f; acc[mi][ni][1] = 0.f;
            acc[mi][ni][2] = 0.f; acc[mi][ni][3] = 0.f;
        }

    for (int kt = 0; kt < 16; ++kt) {
        #pragma unroll
        for (int i = 0; i < 2; ++i) {
            int c = tid + i * 256;
            int row = c >> 2, q = (c & 3) << 3;
            *(s8v*)&Alds[row][q] = *(const s8v*)(A  + (size_t)(m0 + row) * 512 + kt * 32 + q);
            *(s8v*)&Bhl[row][q]  = *(const s8v*)(Bh + (size_t)(n0 + row) * 512 + kt * 32 + q);
            *(s8v*)&Bll[row][q]  = *(const s8v*)(Bl + (size_t)(n0 + row) * 512 + kt * 32 + q);
        }
        __syncthreads();
        s8v af[4], bhf[4], blf[4];
        #pragma unroll
        for (int i = 0; i < 4; ++i) {
            af[i]  = *(const s8v*)&Alds[wr * 64 + i * 16 + lr][kg * 8];
            bhf[i] = *(const s8v*)&Bhl[wc * 64 + i * 16 + lr][kg * 8];
            blf[i] = *(const s8v*)&Bll[wc * 64 + i * 16 + lr][kg * 8];
        }
        #pragma unroll
        for (int mi = 0; mi < 4; ++mi)
            #pragma unroll
            for (int ni = 0; ni < 4; ++ni) {
                acc[mi][ni] = mf16(af[mi], bhf[ni], acc[mi][ni]);
                acc[mi][ni] = mf16(af[mi], blf[ni], acc[mi][ni]);
            }
        __syncthreads();
    }

    #pragma unroll
    for (int mi = 0; mi < 4; ++mi)
        #pragma unroll
        for (int ni = 0; ni < 4; ++ni) {
            int n = n0 + wc * 64 + ni * 16 + lr;
            #pragma unroll
            for (int r = 0; r < 4; ++r) {
                int m = m0 + wr * 64 + mi * 16 + kg * 4 + r;
                out[(size_t)m * 2048 + n] = acc[mi][ni][r];
            }
        }
}

// ---------------- persistent recurrence ------------------------------------
// 64 blocks x 512 threads (8 waves). Block bl: layer=bl>>5, j0=(bl&31)*16.
// Wave w2: gate g=w2&3, K-half kh=w2>>2.
// h0 ring depth 8: write it&7, read (it-1)&7. h1: write (it+1)&1, read it&1.
__global__ __launch_bounds__(512, 1) void rnn_k(
    const float* __restrict__ W1f, const float* __restrict__ U0f,
    const float* __restrict__ U1f,
    const float* __restrict__ bias,
    const float* __restrict__ Gx,   // [4096][2048] fp32
    short* __restrict__ hbuf,       // h0[8][32][512] then h1[2][32][512]
    short* __restrict__ adec,       // [128*32][512] bf16
    unsigned* __restrict__ bar)     // flags0[0..31], flags1[32..63]
{
    const int tid   = threadIdx.x;
    const int bl    = blockIdx.x;
    const int layer = bl >> 5;
    const int j0    = (bl & 31) * 16;
    const int w2    = tid >> 6;       // 0..7
    const int g     = w2 & 3;         // gate
    const int kh    = w2 >> 2;        // K-half
    const int l     = tid & 63;
    const int lr    = l & 15;
    const int kg    = l >> 4;

    __shared__ short Alds[32][1032];
    __shared__ float gbuf[2][4][16][33];      // [kh][gate][j][batch(+pad)]

    // --- one-time: weight slice fp32 -> hi/lo bf16 fragments in VGPRs -------
    const int gr = g * 512 + j0 + lr;         // gate-row in [0,2048)
    s8v wh[16], wlo[16];
    if (layer == 0) {
        #pragma unroll
        for (int ks = 0; ks < 8; ++ks) {
            const float* src = U0f + (size_t)gr * 512 + kh * 256 + ks * 32 + kg * 8;
            float4 va = *(const float4*)src;
            float4 vb = *(const float4*)(src + 4);
            float vv[8] = {va.x, va.y, va.z, va.w, vb.x, vb.y, vb.z, vb.w};
            s8v hi, lo;
            #pragma unroll
            for (int e = 0; e < 8; ++e) {
                short h = f2bf(vv[e]);
                hi[e] = h; lo[e] = f2bf(vv[e] - bf2f(h));
            }
            wh[ks] = hi; wlo[ks] = lo;
        }
    } else {
        const float* base = kh ? U1f : W1f;   // kh=0: W1 (vs h0), kh=1: U1 (vs h1)
        #pragma unroll
        for (int ks = 0; ks < 16; ++ks) {
            const float* src = base + (size_t)gr * 512 + ks * 32 + kg * 8;
            float4 va = *(const float4*)src;
            float4 vb = *(const float4*)(src + 4);
            float vv[8] = {va.x, va.y, va.z, va.w, vb.x, vb.y, vb.z, vb.w};
            s8v hi, lo;
            #pragma unroll
            for (int e = 0; e < 8; ++e) {
                short h = f2bf(vv[e]);
                hi[e] = h; lo[e] = f2bf(vv[e] - bf2f(h));
            }
            wh[ks] = hi; wlo[ks] = lo;
        }
    }

    // --- epilogue ownership: thread -> (batch eb, single j = j0+ej) ---------
    const int eb = tid >> 4;                  // 0..31
    const int ej = tid & 15;                  // 0..15
    const int jj = j0 + ej;
    const float bi = bias[jj];
    const float bf_ = bias[512 + jj];
    const float bg = bias[1024 + jj];
    const float bo = bias[1536 + jj];
    float cst = 0.f;

    short* h0r = hbuf;                        // [8][32][512]
    short* h1r = hbuf + 8 * BAT * HID;        // [2][32][512]

    for (int it = 0; it <= SEQ; ++it) {
        const bool active = (layer == 0) ? (it < SEQ) : (it >= 1);
        const unsigned itu = (unsigned)it;
        const int s0w = it & 7;               // h0 write slot
        const int s0r = (it + 7) & 7;         // h0 read slot  (it-1)
        const int s1w = (it + 1) & 1;         // h1 write slot (it-1)
        const int s1r = it & 1;               // h1 read slot  (it-2)

        if (layer == 0) {
            // prefetch Gx (cached) before any wait
            float gx0 = 0.f, gx1 = 0.f, gx2 = 0.f, gx3 = 0.f;
            if (active) {
                const float* gp = Gx + ((size_t)it * BAT + eb) * 2048 + jj;
                gx0 = gp[0]; gx1 = gp[512]; gx2 = gp[1024]; gx3 = gp[1536];
            }
            // RAW: own layer's previous step
            if (it > 0) {
                if (w2 == 0) pollwait(bar, l, itu, 0u);
                __syncthreads();
            }
            if (active) {
                const short* s = h0r + s0r * BAT * HID;   // h0(it-1)
                #pragma unroll
                for (int i = 0; i < 8; ++i) {
                    int c    = tid + i * 512;
                    int row  = c >> 7;
                    int col4 = (c & 127) * 4;
                    *(u64*)&Alds[row][col4] = cohload8(s + row * HID + col4);
                }
            }
            __syncthreads();
            if (active) {
                f4v a0h, a0l, a1h, a1l;
                a0h[0]=0.f; a0h[1]=0.f; a0h[2]=0.f; a0h[3]=0.f;
                a0l = a0h; a1h = a0h; a1l = a0h;
                #pragma unroll
                for (int ks = 0; ks < 8; ++ks) {
                    const int k = kh * 256 + ks * 32 + kg * 8;
                    s8v a0 = *(const s8v*)&Alds[lr][k];
                    s8v a1 = *(const s8v*)&Alds[16 + lr][k];
                    a0h = mf16(a0, wh[ks],  a0h);
                    a0l = mf16(a0, wlo[ks], a0l);
                    a1h = mf16(a1, wh[ks],  a1h);
                    a1l = mf16(a1, wlo[ks], a1l);
                }
                #pragma unroll
                for (int r = 0; r < 4; ++r) {
                    gbuf[kh][g][lr][kg * 4 + r]      = a0h[r] + a0l[r];
                    gbuf[kh][g][lr][16 + kg * 4 + r] = a1h[r] + a1l[r];
                }
            }
            __syncthreads();
            unsigned short hs = 0;
            if (active) {
                float si = gbuf[0][0][ej][eb] + gbuf[1][0][ej][eb] + gx0;
                float sf = gbuf[0][1][ej][eb] + gbuf[1][1][ej][eb] + gx1;
                float sg = gbuf[0][2][ej][eb] + gbuf[1][2][ej][eb] + gx2;
                float so = gbuf[0][3][ej][eb] + gbuf[1][3][ej][eb] + gx3;
                float gi = sigm(si + bi);
                float gf = sigm(sf + bf_);
                float gg = tanhf(sg + bg);
                float go = sigm(so + bo);
                cst = gf * cst + gi * gg;
                hs = (unsigned short)f2bf(go * tanhf(cst));
            }
            // WAR gate (ring depth 8): layer1 must be past staging of this slot
            if (it >= 7) {
                if (w2 == 0) pollwait(bar, l, 0u, itu - 6u);
                __syncthreads();
            }
            if (active)
                cohstore2(h0r + s0w * BAT * HID + eb * HID + jj, hs);
            if (it < SEQ) {
                asm volatile("s_waitcnt vmcnt(0)" ::: "memory");
                __syncthreads();
                if (tid == 0)
                    __hip_atomic_store(bar + (bl & 31), itu + 1u,
                                       __ATOMIC_RELAXED, __HIP_MEMORY_SCOPE_AGENT);
            }
        } else {
            // ---- layer 1 ----
            // RAW on h0(it-1): flags0 >= it (layer0 runs ahead; usually instant)
            if (it > 0) {
                if (w2 == 0) pollwait(bar, l, itu, 0u);
                __syncthreads();
            }
            if (active) {
                const short* sA = h0r + s0r * BAT * HID;  // h0(it-1)
                #pragma unroll
                for (int i = 0; i < 8; ++i) {
                    int c    = tid + i * 512;
                    int row  = c >> 7;
                    int col4 = (c & 127) * 4;
                    *(u64*)&Alds[row][col4] = cohload8(sA + row * HID + col4);
                }
            }
            // RAW+WAR on h1: flags1 >= it (the pacing chain)
            if (it > 0) {
                if (w2 == 0) pollwait(bar, l, 0u, itu);
                __syncthreads();
            }
            if (active) {
                const short* sB = h1r + s1r * BAT * HID;  // h1(it-2)
                #pragma unroll
                for (int i = 0; i < 8; ++i) {
                    int c    = tid + i * 512;
                    int row  = c >> 7;
                    int col4 = (c & 127) * 4;
                    *(u64*)&Alds[row][512 + col4] = cohload8(sB + row * HID + col4);
                }
            }
            __syncthreads();
            if (active) {
                f4v a0h, a0l, a1h, a1l;
                a0h[0]=0.f; a0h[1]=0.f; a0h[2]=0.f; a0h[3]=0.f;
                a0l = a0h; a1h = a0h; a1l = a0h;
                #pragma unroll
                for (int ks = 0; ks < 16; ++ks) {
                    const int k = kh * 512 + ks * 32 + kg * 8;
                    s8v a0 = *(const s8v*)&Alds[lr][k];
                    s8v a1 = *(const s8v*)&Alds[16 + lr][k];
                    a0h = mf16(a0, wh[ks],  a0h);
                    a0l = mf16(a0, wlo[ks], a0l);
                    a1h = mf16(a1, wh[ks],  a1h);
                    a1l = mf16(a1, wlo[ks], a1l);
                }
                #pragma unroll
                for (int r = 0; r < 4; ++r) {
                    gbuf[kh][g][lr][kg * 4 + r]      = a0h[r] + a0l[r];
                    gbuf[kh][g][lr][16 + kg * 4 + r] = a1h[r] + a1l[r];
                }
            }
            __syncthreads();
            unsigned short hs = 0;
            if (active) {
                float si = gbuf[0][0][ej][eb] + gbuf[1][0][ej][eb];
                float sf = gbuf[0][1][ej][eb] + gbuf[1][1][ej][eb];
                float sg = gbuf[0][2][ej][eb] + gbuf[1][2][ej][eb];
                float so = gbuf[0][3][ej][eb] + gbuf[1][3][ej][eb];
                float gi = sigm(si + bi);
                float gf = sigm(sf + bf_);
                float gg = tanhf(sg + bg);
                float go = sigm(so + bo);
                cst = gf * cst + gi * gg;
                hs = (unsigned short)f2bf(go * tanhf(cst));
                cohstore2(h1r + s1w * BAT * HID + eb * HID + jj, hs);
            }
            if (it < SEQ) {
                asm volatile("s_waitcnt vmcnt(0)" ::: "memory");
                __syncthreads();
                if (tid == 0)
                    __hip_atomic_store(bar + 32 + (bl & 31), itu + 1u,
                                       __ATOMIC_RELAXED, __HIP_MEMORY_SCOPE_AGENT);
            }
            if (active)
                adec[((size_t)(it - 1) * BAT + eb) * HID + jj] = (short)hs;
        }
    }
}

// ---------------- decoder GEMM ---------------------------------------------
__global__ __launch_bounds__(256) void dec_gemm(
    const short* __restrict__ A,    // [4096][512] bf16
    const short* __restrict__ Bw,   // [32000][512] bf16
    const float* __restrict__ bias, // [32000]
    float* __restrict__ out)        // [4096][32000]
{
    const int nb = blockIdx.x % 250, mb = blockIdx.x / 250;
    const int m0 = mb * 128, n0 = nb * 128;
    __shared__ short Alds[128][40];
    __shared__ short Blds[128][40];
    const int tid = threadIdx.x, l = tid & 63, w = tid >> 6;
    const int wr = w >> 1, wc = w & 1;
    const int lr = l & 15, kg = l >> 4;

    f4v acc[4][4];
    #pragma unroll
    for (int mi = 0; mi < 4; ++mi)
        #pragma unroll
        for (int ni = 0; ni < 4; ++ni) {
            acc[mi][ni][0] = 0.f; acc[mi][ni][1] = 0.f;
            acc[mi][ni][2] = 0.f; acc[mi][ni][3] = 0.f;
        }

    for (int kt = 0; kt < 16; ++kt) {
        #pragma unroll
        for (int i = 0; i < 2; ++i) {
            int c = tid + i * 256;
            int row = c >> 2, q = (c & 3) << 3;
            *(s8v*)&Alds[row][q] = *(const s8v*)(A  + (size_t)(m0 + row) * 512 + kt * 32 + q);
            *(s8v*)&Blds[row][q] = *(const s8v*)(Bw + (size_t)(n0 + row) * 512 + kt * 32 + q);
        }
        __syncthreads();
        s8v af[4], bfr[4];
        #pragma unroll
        for (int i = 0; i < 4; ++i) {
            af[i]  = *(const s8v*)&Alds[wr * 64 + i * 16 + lr][kg * 8];
            bfr[i] = *(const s8v*)&Blds[wc * 64 + i * 16 + lr][kg * 8];
        }
        #pragma unroll
        for (int mi = 0; mi < 4; ++mi)
            #pragma unroll
            for (int ni = 0; ni < 4; ++ni)
                acc[mi][ni] = mf16(af[mi], bfr[ni], acc[mi][ni]);
        __syncthreads();
    }

    #pragma unroll
    for (int mi = 0; mi < 4; ++mi)
        #pragma unroll
        for (int ni = 0; ni < 4; ++ni) {
            int n = n0 + wc * 64 + ni * 16 + lr;
            float bb = bias[n];
            #pragma unroll
            for (int r = 0; r < 4; ++r) {
                int m = m0 + wr * 64 + mi * 16 + kg * 4 + r;
                out[(size_t)m * NVOC + n] = acc[mi][ni][r] + bb;
            }
        }
}

extern "C" void kernel_launch(void* const* d_in, const int* in_sizes, int n_in,
                              void* d_out, int out_size, void* d_ws, size_t ws_size,
                              hipStream_t stream)
{
    const int*   toks = (const int*)d_in[0];
    const float* emb  = (const float*)d_in[1];
    const float* W0   = (const float*)d_in[2];
    const float* W1   = (const float*)d_in[3];
    const float* U0   = (const float*)d_in[4];
    const float* U1   = (const float*)d_in[5];
    const float* bias = (const float*)d_in[6];
    const float* dw   = (const float*)d_in[7];
    const float* db   = (const float*)d_in[8];
    float* out = (float*)d_out;

    char* ws = (char*)d_ws;
    size_t off = 0;
    auto alloc = [&](size_t bytes) -> void* {
        void* p = ws + off;
        off += (bytes + 255) & ~(size_t)255;
        return p;
    };
    short*    dbf  = (short*)alloc((size_t)NVOC * DIM * 2);
    short*    xemb = (short*)alloc((size_t)SEQ * BAT * DIM * 2);
    short*    w0h  = (short*)alloc(2048ull * 512 * 2);
    short*    w0l  = (short*)alloc(2048ull * 512 * 2);
    float*    Gx   = (float*)alloc((size_t)SEQ * BAT * 2048 * 4);
    short*    hbuf = (short*)alloc(10ull * BAT * HID * 2);
    short*    adec = (short*)alloc((size_t)SEQ * BAT * HID * 2);
    unsigned* bar  = (unsigned*)alloc(256);

    prep_dec<<<(NVOC * DIM / 4 + 255) / 256, 256, 0, stream>>>(dw, dbf);
    prep_w0 <<<(2048 * 512 + 255) / 256, 256, 0, stream>>>(W0, w0h, w0l);
    embed_k <<<(SEQ * BAT * DIM / 4 + 255) / 256, 256, 0, stream>>>(toks, emb, xemb);
    init_k  <<<(10 * BAT * HID + 255) / 256, 256, 0, stream>>>(hbuf, bar);

    gx_gemm<<<32 * 16, 256, 0, stream>>>(xemb, w0h, w0l, Gx);

    rnn_k<<<NB, 512, 0, stream>>>(W1, U0, U1, bias, Gx, hbuf, adec, bar);

    dec_gemm<<<(SEQ * BAT / 128) * (NVOC / 128), 256, 0, stream>>>(adec, dbf, db, out);
}